// Round 1
// baseline (1107.532 us; speedup 1.0000x reference)
//
#include <hip/hip_runtime.h>

#define NEG_SLOPE 0.2f
#define LN_EPS 1e-5f

// ---------------- CSR build ----------------

__global__ void hist_kernel(const int* __restrict__ dst, int* __restrict__ counts, int E) {
    int i = blockIdx.x * blockDim.x + threadIdx.x;
    if (i < E) atomicAdd(&counts[dst[i]], 1);
}

// Single-block exclusive scan over counts[n] -> rowptr[n+1]; also rewrites
// counts[] in place as the scatter cursor (safe: per-index read-before-write,
// disjoint thread ranges).
__global__ void scan_kernel(int* __restrict__ counts, int* __restrict__ rowptr, int n, int E) {
    __shared__ int lds[1024];
    int t = threadIdx.x;
    int chunk = (n + 1023) / 1024;
    int begin = t * chunk;
    int end = min(begin + chunk, n);
    int sum = 0;
    for (int i = begin; i < end; ++i) sum += counts[i];
    lds[t] = sum;
    __syncthreads();
    for (int off = 1; off < 1024; off <<= 1) {
        int v = (t >= off) ? lds[t - off] : 0;
        __syncthreads();
        lds[t] += v;
        __syncthreads();
    }
    int run = lds[t] - sum;  // exclusive prefix
    for (int i = begin; i < end; ++i) {
        int c = counts[i];
        rowptr[i] = run;
        counts[i] = run;  // cursor for scatter
        run += c;
    }
    if (t == 1023) rowptr[n] = E;
}

__global__ void scatter_kernel(const int* __restrict__ src, const int* __restrict__ dst,
                               const float* __restrict__ ew, int* __restrict__ cursor,
                               int* __restrict__ src_s, float* __restrict__ ew_s, int E) {
    int i = blockIdx.x * blockDim.x + threadIdx.x;
    if (i < E) {
        int p = atomicAdd(&cursor[dst[i]], 1);
        src_s[p] = src[i];
        ew_s[p] = ew[i];
    }
}

// ---------------- GEMM: C[n,K] = A[n,128] @ W[128,K] ----------------

template <int K>
__global__ __launch_bounds__(256) void gemm_kernel(const float* __restrict__ A,
                                                   const float* __restrict__ W,
                                                   float* __restrict__ C, int n) {
    __shared__ float Wl[128 * K];  // K=128 -> 64KB
    int t = threadIdx.x;
    const float4* W4 = (const float4*)W;
    float4* Wl4 = (float4*)Wl;
    constexpr int WV = 128 * K / 4;
    #pragma unroll
    for (int i = 0; i < WV / 256; ++i) Wl4[t + i * 256] = W4[t + i * 256];
    __syncthreads();

    constexpr int CG = K / 4;     // col groups of 4
    constexpr int RPT = CG / 8;   // rows per thread (K=128 -> 4, K=64 -> 2)
    int cg = t % CG, rg = t / CG;
    int row0 = blockIdx.x * 32 + rg * RPT;
    const float4* A4 = (const float4*)A;

    float acc[RPT][4] = {};
    for (int k4 = 0; k4 < 32; ++k4) {
        float a[RPT][4];
        #pragma unroll
        for (int r = 0; r < RPT; ++r) {
            int row = row0 + r;
            float4 v = (row < n) ? A4[(size_t)row * 32 + k4] : make_float4(0, 0, 0, 0);
            a[r][0] = v.x; a[r][1] = v.y; a[r][2] = v.z; a[r][3] = v.w;
        }
        #pragma unroll
        for (int j = 0; j < 4; ++j) {
            float4 wv = Wl4[(k4 * 4 + j) * CG + cg];
            #pragma unroll
            for (int r = 0; r < RPT; ++r) {
                acc[r][0] = fmaf(a[r][j], wv.x, acc[r][0]);
                acc[r][1] = fmaf(a[r][j], wv.y, acc[r][1]);
                acc[r][2] = fmaf(a[r][j], wv.z, acc[r][2]);
                acc[r][3] = fmaf(a[r][j], wv.w, acc[r][3]);
            }
        }
    }
    #pragma unroll
    for (int r = 0; r < RPT; ++r) {
        int row = row0 + r;
        if (row < n)
            *((float4*)&C[(size_t)row * K + cg * 4]) =
                make_float4(acc[r][0], acc[r][1], acc[r][2], acc[r][3]);
    }
}

// ---------------- el/er: [n,H] attention logit halves ----------------

__global__ void elr_kernel(const float* __restrict__ ft, const float* __restrict__ al,
                           const float* __restrict__ ar, float* __restrict__ el,
                           float* __restrict__ er, int n, int H, int D, int HD) {
    int i = blockIdx.x * blockDim.x + threadIdx.x;
    if (i >= n * H) return;
    int node = i / H, h = i - node * H;
    const float4* f4 = (const float4*)(ft + (size_t)node * HD + h * D);
    const float4* a4 = (const float4*)(al + h * D);
    const float4* r4 = (const float4*)(ar + h * D);
    float sl = 0.f, sr = 0.f;
    for (int d = 0; d < D / 4; ++d) {
        float4 f = f4[d], a = a4[d], r = r4[d];
        sl += f.x * a.x + f.y * a.y + f.z * a.z + f.w * a.w;
        sr += f.x * r.x + f.y * r.y + f.z * r.z + f.w * r.w;
    }
    el[i] = sl;
    er[i] = sr;
}

// ---------------- fused GAT aggregate + ELU + LayerNorm + residual ----------------
// One wave per dst node. HD=128: float2 per lane; head = lane/16.

__global__ __launch_bounds__(256) void gat_agg_ln(
    const int* __restrict__ rowptr, const int* __restrict__ src_s,
    const float* __restrict__ ew_s, const float* __restrict__ ft,
    const float* __restrict__ el, const float* __restrict__ er,
    const float* __restrict__ lam_p, const float* __restrict__ g,
    const float* __restrict__ b, const float* __restrict__ prev,
    float* __restrict__ out, int n) {
    int wid = blockIdx.x * 4 + (threadIdx.x >> 6);
    if (wid >= n) return;
    int lane = threadIdx.x & 63;
    int head = lane >> 4;
    float lam = lam_p[0];
    float erv = er[wid * 4 + head];
    int s0 = rowptr[wid], s1 = rowptr[wid + 1];
    const float2* ft2 = (const float2*)ft;
    float ax = 0.f, ay = 0.f, s = 0.f;
    for (int i = s0; i < s1; ++i) {
        int sn = src_s[i];
        float wgt = ew_s[i];
        float e = el[sn * 4 + head] + erv + lam * wgt;
        e = (e >= 0.f) ? e : NEG_SLOPE * e;
        float p = __expf(e);
        float2 f = ft2[(size_t)sn * 64 + lane];
        ax = fmaf(p, f.x, ax);
        ay = fmaf(p, f.y, ay);
        s += p;
    }
    float inv = (s > 0.f) ? 1.f / s : 0.f;
    float x0 = ax * inv, x1 = ay * inv;
    // ELU
    x0 = (x0 > 0.f) ? x0 : expm1f(x0);
    x1 = (x1 > 0.f) ? x1 : expm1f(x1);
    // LayerNorm over 128 dims spread across 64 lanes
    float sum = x0 + x1, sq = x0 * x0 + x1 * x1;
    #pragma unroll
    for (int off = 32; off > 0; off >>= 1) {
        sum += __shfl_xor(sum, off, 64);
        sq += __shfl_xor(sq, off, 64);
    }
    float mu = sum * (1.f / 128.f);
    float var = sq * (1.f / 128.f) - mu * mu;
    float rs = rsqrtf(var + LN_EPS);
    float2 gv = ((const float2*)g)[lane];
    float2 bv = ((const float2*)b)[lane];
    float2 pv = ((const float2*)prev)[(size_t)wid * 64 + lane];
    float2 y;
    y.x = (x0 - mu) * rs * gv.x + bv.x + pv.x;
    y.y = (x1 - mu) * rs * gv.y + bv.y + pv.y;
    ((float2*)out)[(size_t)wid * 64 + lane] = y;
}

// Layer 2: H=1, OUT=64, no epilogue; writes both tuple halves.
__global__ __launch_bounds__(256) void gat_agg_out(
    const int* __restrict__ rowptr, const int* __restrict__ src_s,
    const float* __restrict__ ew_s, const float* __restrict__ ft,
    const float* __restrict__ el, const float* __restrict__ er,
    const float* __restrict__ lam_p, float* __restrict__ out, int n) {
    int wid = blockIdx.x * 4 + (threadIdx.x >> 6);
    if (wid >= n) return;
    int lane = threadIdx.x & 63;
    float lam = lam_p[0];
    float erv = er[wid];
    int s0 = rowptr[wid], s1 = rowptr[wid + 1];
    float acc = 0.f, s = 0.f;
    for (int i = s0; i < s1; ++i) {
        int sn = src_s[i];
        float wgt = ew_s[i];
        float e = el[sn] + erv + lam * wgt;
        e = (e >= 0.f) ? e : NEG_SLOPE * e;
        float p = __expf(e);
        acc = fmaf(p, ft[(size_t)sn * 64 + lane], acc);
        s += p;
    }
    float inv = (s > 0.f) ? 1.f / s : 0.f;
    float v = acc * inv;
    out[(size_t)wid * 64 + lane] = v;
    out[(size_t)n * 64 + (size_t)wid * 64 + lane] = v;
}

// ---------------- launch ----------------

extern "C" void kernel_launch(void* const* d_in, const int* in_sizes, int n_in,
                              void* d_out, int out_size, void* d_ws, size_t ws_size,
                              hipStream_t stream) {
    const float* features = (const float*)d_in[0];
    const float* edge_weight = (const float*)d_in[1];
    const int* src = (const int*)d_in[2];
    const int* dst = (const int*)d_in[3];
    const float* W0 = (const float*)d_in[4];
    const float* al0 = (const float*)d_in[5];
    const float* ar0 = (const float*)d_in[6];
    const float* lam0 = (const float*)d_in[7];
    const float* W1 = (const float*)d_in[8];
    const float* al1 = (const float*)d_in[9];
    const float* ar1 = (const float*)d_in[10];
    const float* lam1 = (const float*)d_in[11];
    const float* W2 = (const float*)d_in[12];
    const float* al2 = (const float*)d_in[13];
    const float* ar2 = (const float*)d_in[14];
    const float* lam2 = (const float*)d_in[15];
    const float* g0 = (const float*)d_in[16];
    const float* b0 = (const float*)d_in[17];
    const float* g1 = (const float*)d_in[18];
    const float* b1 = (const float*)d_in[19];

    const int N = in_sizes[0] / 128;
    const int E = in_sizes[1];

    char* w = (char*)d_ws;
    size_t o = 0;
    auto carve = [&](size_t bytes) {
        char* p = w + o;
        o += (bytes + 255) & ~(size_t)255;
        return p;
    };
    int* counts = (int*)carve((size_t)N * 4);        // doubles as scatter cursor
    int* rowptr = (int*)carve((size_t)(N + 1) * 4);
    int* src_s = (int*)carve((size_t)E * 4);
    float* ew_s = (float*)carve((size_t)E * 4);
    float* ft = (float*)carve((size_t)N * 128 * 4);
    float* el = (float*)carve((size_t)N * 4 * 4);
    float* er = (float*)carve((size_t)N * 4 * 4);
    float* h1 = (float*)carve((size_t)N * 128 * 4);
    float* h2 = (float*)carve((size_t)N * 128 * 4);

    // CSR by dst (shared across the 3 layers)
    hipMemsetAsync(counts, 0, (size_t)N * 4, stream);
    hist_kernel<<<(E + 255) / 256, 256, 0, stream>>>(dst, counts, E);
    scan_kernel<<<1, 1024, 0, stream>>>(counts, rowptr, N, E);
    scatter_kernel<<<(E + 255) / 256, 256, 0, stream>>>(src, dst, edge_weight, counts,
                                                        src_s, ew_s, E);

    // Layer 0
    gemm_kernel<128><<<(N + 31) / 32, 256, 0, stream>>>(features, W0, ft, N);
    elr_kernel<<<(N * 4 + 255) / 256, 256, 0, stream>>>(ft, al0, ar0, el, er, N, 4, 32, 128);
    gat_agg_ln<<<(N + 3) / 4, 256, 0, stream>>>(rowptr, src_s, ew_s, ft, el, er, lam0,
                                                g0, b0, features, h1, N);
    // Layer 1
    gemm_kernel<128><<<(N + 31) / 32, 256, 0, stream>>>(h1, W1, ft, N);
    elr_kernel<<<(N * 4 + 255) / 256, 256, 0, stream>>>(ft, al1, ar1, el, er, N, 4, 32, 128);
    gat_agg_ln<<<(N + 3) / 4, 256, 0, stream>>>(rowptr, src_s, ew_s, ft, el, er, lam1,
                                                g1, b1, h1, h2, N);
    // Layer 2
    gemm_kernel<64><<<(N + 31) / 32, 256, 0, stream>>>(h2, W2, ft, N);
    elr_kernel<<<(N + 255) / 256, 256, 0, stream>>>(ft, al2, ar2, el, er, N, 1, 64, 64);
    gat_agg_out<<<(N + 3) / 4, 256, 0, stream>>>(rowptr, src_s, ew_s, ft, el, er, lam2,
                                                 (float*)d_out, N);
}

// Round 2
// 758.430 us; speedup vs baseline: 1.4603x; 1.4603x over previous
//
#include <hip/hip_runtime.h>

#define NEG_SLOPE 0.2f
#define LN_EPS 1e-5f

// ---------------- CSR build ----------------

__global__ void hist_kernel(const int* __restrict__ dst, int* __restrict__ counts, int E) {
    int i = blockIdx.x * blockDim.x + threadIdx.x;
    if (i < E) atomicAdd(&counts[dst[i]], 1);
}

// Single-block exclusive scan over counts[n] -> rowptr[n+1]; also rewrites
// counts[] in place as the scatter cursor.
__global__ void scan_kernel(int* __restrict__ counts, int* __restrict__ rowptr, int n, int E) {
    __shared__ int lds[1024];
    int t = threadIdx.x;
    int chunk = (n + 1023) / 1024;
    int begin = t * chunk;
    int end = min(begin + chunk, n);
    int sum = 0;
    for (int i = begin; i < end; ++i) sum += counts[i];
    lds[t] = sum;
    __syncthreads();
    for (int off = 1; off < 1024; off <<= 1) {
        int v = (t >= off) ? lds[t - off] : 0;
        __syncthreads();
        lds[t] += v;
        __syncthreads();
    }
    int run = lds[t] - sum;  // exclusive prefix
    for (int i = begin; i < end; ++i) {
        int c = counts[i];
        rowptr[i] = run;
        counts[i] = run;  // cursor for scatter
        run += c;
    }
    if (t == 1023) rowptr[n] = E;
}

__global__ void scatter_kernel(const int* __restrict__ src, const int* __restrict__ dst,
                               const float* __restrict__ ew, int* __restrict__ cursor,
                               int* __restrict__ src_s, float* __restrict__ ew_s, int E) {
    int i = blockIdx.x * blockDim.x + threadIdx.x;
    if (i < E) {
        int p = atomicAdd(&cursor[dst[i]], 1);
        src_s[p] = src[i];
        ew_s[p] = ew[i];
    }
}

// ---------------- GEMM: C[n,K] = A[n,128] @ W[128,K] ----------------
// 32 rows x K cols per block; W staged in LDS in 32-k chunks (16 KB for K=128)
// to keep occupancy high and VGPRs < 128 (R0 regression: full-W 64 KB LDS +
// fully-unrolled staging spilled ~870 MB of scratch per dispatch).

template <int K>
__global__ __launch_bounds__(256) void gemm_kernel(const float* __restrict__ A,
                                                   const float* __restrict__ W,
                                                   float* __restrict__ C, int n) {
    constexpr int CG = K / 4;          // float4 col-groups per row
    constexpr int RPT = CG / 8;        // rows per thread (K=128 -> 4, K=64 -> 2)
    constexpr int CHUNK_V = 32 * CG;   // float4s per 32-k chunk of W
    __shared__ float4 Wl4[CHUNK_V];

    int t = threadIdx.x;
    int cg = t % CG, rg = t / CG;
    int row0 = blockIdx.x * 32 + rg * RPT;
    const float4* A4 = (const float4*)A;
    const float4* W4 = (const float4*)W;

    float acc[RPT][4] = {};
    for (int c = 0; c < 4; ++c) {   // 4 chunks of 32 k-values
        __syncthreads();
        #pragma unroll
        for (int i = 0; i < CHUNK_V / 256; ++i)
            Wl4[t + i * 256] = W4[c * CHUNK_V + t + i * 256];
        __syncthreads();
        #pragma unroll 2
        for (int k4 = 0; k4 < 8; ++k4) {
            float4 a[RPT];
            #pragma unroll
            for (int r = 0; r < RPT; ++r) {
                int row = row0 + r;
                a[r] = (row < n) ? A4[(size_t)row * 32 + c * 8 + k4]
                                 : make_float4(0.f, 0.f, 0.f, 0.f);
            }
            #pragma unroll
            for (int j = 0; j < 4; ++j) {
                float4 wv = Wl4[(k4 * 4 + j) * CG + cg];
                #pragma unroll
                for (int r = 0; r < RPT; ++r) {
                    float av = (j == 0) ? a[r].x : (j == 1) ? a[r].y : (j == 2) ? a[r].z : a[r].w;
                    acc[r][0] = fmaf(av, wv.x, acc[r][0]);
                    acc[r][1] = fmaf(av, wv.y, acc[r][1]);
                    acc[r][2] = fmaf(av, wv.z, acc[r][2]);
                    acc[r][3] = fmaf(av, wv.w, acc[r][3]);
                }
            }
        }
    }
    #pragma unroll
    for (int r = 0; r < RPT; ++r) {
        int row = row0 + r;
        if (row < n)
            *((float4*)&C[(size_t)row * K + cg * 4]) =
                make_float4(acc[r][0], acc[r][1], acc[r][2], acc[r][3]);
    }
}

// ---------------- el/er: [n,H] attention logit halves ----------------

__global__ void elr_kernel(const float* __restrict__ ft, const float* __restrict__ al,
                           const float* __restrict__ ar, float* __restrict__ el,
                           float* __restrict__ er, int n, int H, int D, int HD) {
    int i = blockIdx.x * blockDim.x + threadIdx.x;
    if (i >= n * H) return;
    int node = i / H, h = i - node * H;
    const float4* f4 = (const float4*)(ft + (size_t)node * HD + h * D);
    const float4* a4 = (const float4*)(al + h * D);
    const float4* r4 = (const float4*)(ar + h * D);
    float sl = 0.f, sr = 0.f;
    for (int d = 0; d < D / 4; ++d) {
        float4 f = f4[d], a = a4[d], r = r4[d];
        sl += f.x * a.x + f.y * a.y + f.z * a.z + f.w * a.w;
        sr += f.x * r.x + f.y * r.y + f.z * r.z + f.w * r.w;
    }
    el[i] = sl;
    er[i] = sr;
}

// ---------------- fused GAT aggregate + ELU + LayerNorm + residual ----------------
// One wave per dst node. HD=128: float2 per lane; head = lane/16.

__global__ __launch_bounds__(256) void gat_agg_ln(
    const int* __restrict__ rowptr, const int* __restrict__ src_s,
    const float* __restrict__ ew_s, const float* __restrict__ ft,
    const float* __restrict__ el, const float* __restrict__ er,
    const float* __restrict__ lam_p, const float* __restrict__ g,
    const float* __restrict__ b, const float* __restrict__ prev,
    float* __restrict__ out, int n) {
    int wid = blockIdx.x * 4 + (threadIdx.x >> 6);
    if (wid >= n) return;
    int lane = threadIdx.x & 63;
    int head = lane >> 4;
    float lam = lam_p[0];
    float erv = er[wid * 4 + head];
    int s0 = rowptr[wid], s1 = rowptr[wid + 1];
    const float2* ft2 = (const float2*)ft;
    float ax = 0.f, ay = 0.f, s = 0.f;
    for (int i = s0; i < s1; ++i) {
        int sn = src_s[i];
        float wgt = ew_s[i];
        float e = el[sn * 4 + head] + erv + lam * wgt;
        e = (e >= 0.f) ? e : NEG_SLOPE * e;
        float p = __expf(e);
        float2 f = ft2[(size_t)sn * 64 + lane];
        ax = fmaf(p, f.x, ax);
        ay = fmaf(p, f.y, ay);
        s += p;
    }
    float inv = (s > 0.f) ? 1.f / s : 0.f;
    float x0 = ax * inv, x1 = ay * inv;
    // ELU
    x0 = (x0 > 0.f) ? x0 : expm1f(x0);
    x1 = (x1 > 0.f) ? x1 : expm1f(x1);
    // LayerNorm over 128 dims spread across 64 lanes
    float sum = x0 + x1, sq = x0 * x0 + x1 * x1;
    #pragma unroll
    for (int off = 32; off > 0; off >>= 1) {
        sum += __shfl_xor(sum, off, 64);
        sq += __shfl_xor(sq, off, 64);
    }
    float mu = sum * (1.f / 128.f);
    float var = sq * (1.f / 128.f) - mu * mu;
    float rs = rsqrtf(var + LN_EPS);
    float2 gv = ((const float2*)g)[lane];
    float2 bv = ((const float2*)b)[lane];
    float2 pv = ((const float2*)prev)[(size_t)wid * 64 + lane];
    float2 y;
    y.x = (x0 - mu) * rs * gv.x + bv.x + pv.x;
    y.y = (x1 - mu) * rs * gv.y + bv.y + pv.y;
    ((float2*)out)[(size_t)wid * 64 + lane] = y;
}

// Layer 2: H=1, OUT=64, no epilogue; writes both tuple halves.
__global__ __launch_bounds__(256) void gat_agg_out(
    const int* __restrict__ rowptr, const int* __restrict__ src_s,
    const float* __restrict__ ew_s, const float* __restrict__ ft,
    const float* __restrict__ el, const float* __restrict__ er,
    const float* __restrict__ lam_p, float* __restrict__ out, int n) {
    int wid = blockIdx.x * 4 + (threadIdx.x >> 6);
    if (wid >= n) return;
    int lane = threadIdx.x & 63;
    float lam = lam_p[0];
    float erv = er[wid];
    int s0 = rowptr[wid], s1 = rowptr[wid + 1];
    float acc = 0.f, s = 0.f;
    for (int i = s0; i < s1; ++i) {
        int sn = src_s[i];
        float wgt = ew_s[i];
        float e = el[sn] + erv + lam * wgt;
        e = (e >= 0.f) ? e : NEG_SLOPE * e;
        float p = __expf(e);
        acc = fmaf(p, ft[(size_t)sn * 64 + lane], acc);
        s += p;
    }
    float inv = (s > 0.f) ? 1.f / s : 0.f;
    float v = acc * inv;
    out[(size_t)wid * 64 + lane] = v;
    out[(size_t)n * 64 + (size_t)wid * 64 + lane] = v;
}

// ---------------- launch ----------------

extern "C" void kernel_launch(void* const* d_in, const int* in_sizes, int n_in,
                              void* d_out, int out_size, void* d_ws, size_t ws_size,
                              hipStream_t stream) {
    const float* features = (const float*)d_in[0];
    const float* edge_weight = (const float*)d_in[1];
    const int* src = (const int*)d_in[2];
    const int* dst = (const int*)d_in[3];
    const float* W0 = (const float*)d_in[4];
    const float* al0 = (const float*)d_in[5];
    const float* ar0 = (const float*)d_in[6];
    const float* lam0 = (const float*)d_in[7];
    const float* W1 = (const float*)d_in[8];
    const float* al1 = (const float*)d_in[9];
    const float* ar1 = (const float*)d_in[10];
    const float* lam1 = (const float*)d_in[11];
    const float* W2 = (const float*)d_in[12];
    const float* al2 = (const float*)d_in[13];
    const float* ar2 = (const float*)d_in[14];
    const float* lam2 = (const float*)d_in[15];
    const float* g0 = (const float*)d_in[16];
    const float* b0 = (const float*)d_in[17];
    const float* g1 = (const float*)d_in[18];
    const float* b1 = (const float*)d_in[19];

    const int N = in_sizes[0] / 128;
    const int E = in_sizes[1];

    char* w = (char*)d_ws;
    size_t o = 0;
    auto carve = [&](size_t bytes) {
        char* p = w + o;
        o += (bytes + 255) & ~(size_t)255;
        return p;
    };
    int* counts = (int*)carve((size_t)N * 4);        // doubles as scatter cursor
    int* rowptr = (int*)carve((size_t)(N + 1) * 4);
    int* src_s = (int*)carve((size_t)E * 4);
    float* ew_s = (float*)carve((size_t)E * 4);
    float* ft = (float*)carve((size_t)N * 128 * 4);
    float* el = (float*)carve((size_t)N * 4 * 4);
    float* er = (float*)carve((size_t)N * 4 * 4);
    float* h1 = (float*)carve((size_t)N * 128 * 4);
    float* h2 = (float*)carve((size_t)N * 128 * 4);

    // CSR by dst (shared across the 3 layers)
    hipMemsetAsync(counts, 0, (size_t)N * 4, stream);
    hist_kernel<<<(E + 255) / 256, 256, 0, stream>>>(dst, counts, E);
    scan_kernel<<<1, 1024, 0, stream>>>(counts, rowptr, N, E);
    scatter_kernel<<<(E + 255) / 256, 256, 0, stream>>>(src, dst, edge_weight, counts,
                                                        src_s, ew_s, E);

    // Layer 0
    gemm_kernel<128><<<(N + 31) / 32, 256, 0, stream>>>(features, W0, ft, N);
    elr_kernel<<<(N * 4 + 255) / 256, 256, 0, stream>>>(ft, al0, ar0, el, er, N, 4, 32, 128);
    gat_agg_ln<<<(N + 3) / 4, 256, 0, stream>>>(rowptr, src_s, ew_s, ft, el, er, lam0,
                                                g0, b0, features, h1, N);
    // Layer 1
    gemm_kernel<128><<<(N + 31) / 32, 256, 0, stream>>>(h1, W1, ft, N);
    elr_kernel<<<(N * 4 + 255) / 256, 256, 0, stream>>>(ft, al1, ar1, el, er, N, 4, 32, 128);
    gat_agg_ln<<<(N + 3) / 4, 256, 0, stream>>>(rowptr, src_s, ew_s, ft, el, er, lam1,
                                                g1, b1, h1, h2, N);
    // Layer 2
    gemm_kernel<64><<<(N + 31) / 32, 256, 0, stream>>>(h2, W2, ft, N);
    elr_kernel<<<(N + 255) / 256, 256, 0, stream>>>(ft, al2, ar2, el, er, N, 1, 64, 64);
    gat_agg_out<<<(N + 3) / 4, 256, 0, stream>>>(rowptr, src_s, ew_s, ft, el, er, lam2,
                                                 (float*)d_out, N);
}

// Round 3
// 649.112 us; speedup vs baseline: 1.7062x; 1.1684x over previous
//
#include <hip/hip_runtime.h>

#define NEG_SLOPE 0.2f
#define LN_EPS 1e-5f

// ---------------- CSR build ----------------

__global__ void hist_kernel(const int* __restrict__ dst, int* __restrict__ counts, int E) {
    int i = blockIdx.x * blockDim.x + threadIdx.x;
    if (i < E) atomicAdd(&counts[dst[i]], 1);
}

// Hierarchical scan, pass 1: per-block sums of counts (256 elems/block).
__global__ __launch_bounds__(256) void scan1_kernel(const int* __restrict__ counts,
                                                    int* __restrict__ bsum, int n) {
    __shared__ int lds[256];
    int t = threadIdx.x;
    int i = blockIdx.x * 256 + t;
    lds[t] = (i < n) ? counts[i] : 0;
    __syncthreads();
    for (int off = 128; off > 0; off >>= 1) {
        int v = (t < off) ? lds[t + off] : 0;
        __syncthreads();
        if (t < off) lds[t] += v;
        __syncthreads();
    }
    if (t == 0) bsum[blockIdx.x] = lds[0];
}

// Pass 2: single tiny block scans the (<=256) block sums -> exclusive.
__global__ __launch_bounds__(256) void scan2_kernel(int* __restrict__ bsum, int nblocks) {
    __shared__ int lds[256];
    int t = threadIdx.x;
    int v0 = (t < nblocks) ? bsum[t] : 0;
    lds[t] = v0;
    __syncthreads();
    for (int off = 1; off < 256; off <<= 1) {
        int v = (t >= off) ? lds[t - off] : 0;
        __syncthreads();
        lds[t] += v;
        __syncthreads();
    }
    if (t < nblocks) bsum[t] = lds[t] - v0;  // exclusive
}

// Pass 3: per-block LDS scan + block offset -> rowptr + scatter cursor.
__global__ __launch_bounds__(256) void scan3_kernel(int* __restrict__ counts,
                                                    const int* __restrict__ bsum,
                                                    int* __restrict__ rowptr, int n, int E) {
    __shared__ int lds[256];
    int t = threadIdx.x;
    int i = blockIdx.x * 256 + t;
    int c = (i < n) ? counts[i] : 0;
    lds[t] = c;
    __syncthreads();
    for (int off = 1; off < 256; off <<= 1) {
        int v = (t >= off) ? lds[t - off] : 0;
        __syncthreads();
        lds[t] += v;
        __syncthreads();
    }
    int ex = bsum[blockIdx.x] + lds[t] - c;  // exclusive prefix
    if (i < n) {
        rowptr[i] = ex;
        counts[i] = ex;  // cursor for scatter
    }
    if (i == n) rowptr[n] = E;
}

__global__ void scatter_kernel(const int* __restrict__ src, const int* __restrict__ dst,
                               const float* __restrict__ ew, int* __restrict__ cursor,
                               int* __restrict__ src_s, float* __restrict__ ew_s, int E) {
    int i = blockIdx.x * blockDim.x + threadIdx.x;
    if (i < E) {
        int p = atomicAdd(&cursor[dst[i]], 1);
        src_s[p] = src[i];
        ew_s[p] = ew[i];
    }
}

// ---------------- GEMM: C[n,K] = A[n,128] @ W[128,K] ----------------
// 32 rows x K cols per block; W staged in LDS in 32-k chunks (16 KB for K=128)
// to keep occupancy high and VGPRs < 128 (R0 regression: full-W 64 KB LDS +
// fully-unrolled staging spilled ~870 MB of scratch per dispatch).

template <int K>
__global__ __launch_bounds__(256) void gemm_kernel(const float* __restrict__ A,
                                                   const float* __restrict__ W,
                                                   float* __restrict__ C, int n) {
    constexpr int CG = K / 4;          // float4 col-groups per row
    constexpr int RPT = CG / 8;        // rows per thread (K=128 -> 4, K=64 -> 2)
    constexpr int CHUNK_V = 32 * CG;   // float4s per 32-k chunk of W
    __shared__ float4 Wl4[CHUNK_V];

    int t = threadIdx.x;
    int cg = t % CG, rg = t / CG;
    int row0 = blockIdx.x * 32 + rg * RPT;
    const float4* A4 = (const float4*)A;
    const float4* W4 = (const float4*)W;

    float acc[RPT][4] = {};
    for (int c = 0; c < 4; ++c) {   // 4 chunks of 32 k-values
        __syncthreads();
        #pragma unroll
        for (int i = 0; i < CHUNK_V / 256; ++i)
            Wl4[t + i * 256] = W4[c * CHUNK_V + t + i * 256];
        __syncthreads();
        #pragma unroll 2
        for (int k4 = 0; k4 < 8; ++k4) {
            float4 a[RPT];
            #pragma unroll
            for (int r = 0; r < RPT; ++r) {
                int row = row0 + r;
                a[r] = (row < n) ? A4[(size_t)row * 32 + c * 8 + k4]
                                 : make_float4(0.f, 0.f, 0.f, 0.f);
            }
            #pragma unroll
            for (int j = 0; j < 4; ++j) {
                float4 wv = Wl4[(k4 * 4 + j) * CG + cg];
                #pragma unroll
                for (int r = 0; r < RPT; ++r) {
                    float av = (j == 0) ? a[r].x : (j == 1) ? a[r].y : (j == 2) ? a[r].z : a[r].w;
                    acc[r][0] = fmaf(av, wv.x, acc[r][0]);
                    acc[r][1] = fmaf(av, wv.y, acc[r][1]);
                    acc[r][2] = fmaf(av, wv.z, acc[r][2]);
                    acc[r][3] = fmaf(av, wv.w, acc[r][3]);
                }
            }
        }
    }
    #pragma unroll
    for (int r = 0; r < RPT; ++r) {
        int row = row0 + r;
        if (row < n)
            *((float4*)&C[(size_t)row * K + cg * 4]) =
                make_float4(acc[r][0], acc[r][1], acc[r][2], acc[r][3]);
    }
}

// ---------------- el/er: [n,H] attention logit halves ----------------

__global__ void elr_kernel(const float* __restrict__ ft, const float* __restrict__ al,
                           const float* __restrict__ ar, float* __restrict__ el,
                           float* __restrict__ er, int n, int H, int D, int HD) {
    int i = blockIdx.x * blockDim.x + threadIdx.x;
    if (i >= n * H) return;
    int node = i / H, h = i - node * H;
    const float4* f4 = (const float4*)(ft + (size_t)node * HD + h * D);
    const float4* a4 = (const float4*)(al + h * D);
    const float4* r4 = (const float4*)(ar + h * D);
    float sl = 0.f, sr = 0.f;
    for (int d = 0; d < D / 4; ++d) {
        float4 f = f4[d], a = a4[d], r = r4[d];
        sl += f.x * a.x + f.y * a.y + f.z * a.z + f.w * a.w;
        sr += f.x * r.x + f.y * r.y + f.z * r.z + f.w * r.w;
    }
    el[i] = sl;
    er[i] = sr;
}

// ---------------- fused GAT aggregate + ELU + LayerNorm + residual ----------------
// One wave per dst node. HD=128: float2 per lane; head = lane/16.

__global__ __launch_bounds__(256) void gat_agg_ln(
    const int* __restrict__ rowptr, const int* __restrict__ src_s,
    const float* __restrict__ ew_s, const float* __restrict__ ft,
    const float* __restrict__ el, const float* __restrict__ er,
    const float* __restrict__ lam_p, const float* __restrict__ g,
    const float* __restrict__ b, const float* __restrict__ prev,
    float* __restrict__ out, int n) {
    int wid = blockIdx.x * 4 + (threadIdx.x >> 6);
    if (wid >= n) return;
    int lane = threadIdx.x & 63;
    int head = lane >> 4;
    float lam = lam_p[0];
    float erv = er[wid * 4 + head];
    int s0 = rowptr[wid], s1 = rowptr[wid + 1];
    const float2* ft2 = (const float2*)ft;
    float ax = 0.f, ay = 0.f, s = 0.f;
    for (int i = s0; i < s1; ++i) {
        int sn = src_s[i];
        float wgt = ew_s[i];
        float e = el[sn * 4 + head] + erv + lam * wgt;
        e = (e >= 0.f) ? e : NEG_SLOPE * e;
        float p = __expf(e);
        float2 f = ft2[(size_t)sn * 64 + lane];
        ax = fmaf(p, f.x, ax);
        ay = fmaf(p, f.y, ay);
        s += p;
    }
    float inv = (s > 0.f) ? 1.f / s : 0.f;
    float x0 = ax * inv, x1 = ay * inv;
    // ELU
    x0 = (x0 > 0.f) ? x0 : expm1f(x0);
    x1 = (x1 > 0.f) ? x1 : expm1f(x1);
    // LayerNorm over 128 dims spread across 64 lanes
    float sum = x0 + x1, sq = x0 * x0 + x1 * x1;
    #pragma unroll
    for (int off = 32; off > 0; off >>= 1) {
        sum += __shfl_xor(sum, off, 64);
        sq += __shfl_xor(sq, off, 64);
    }
    float mu = sum * (1.f / 128.f);
    float var = sq * (1.f / 128.f) - mu * mu;
    float rs = rsqrtf(var + LN_EPS);
    float2 gv = ((const float2*)g)[lane];
    float2 bv = ((const float2*)b)[lane];
    float2 pv = ((const float2*)prev)[(size_t)wid * 64 + lane];
    float2 y;
    y.x = (x0 - mu) * rs * gv.x + bv.x + pv.x;
    y.y = (x1 - mu) * rs * gv.y + bv.y + pv.y;
    ((float2*)out)[(size_t)wid * 64 + lane] = y;
}

// Layer 2: H=1, OUT=64, no epilogue; writes both tuple halves.
__global__ __launch_bounds__(256) void gat_agg_out(
    const int* __restrict__ rowptr, const int* __restrict__ src_s,
    const float* __restrict__ ew_s, const float* __restrict__ ft,
    const float* __restrict__ el, const float* __restrict__ er,
    const float* __restrict__ lam_p, float* __restrict__ out, int n) {
    int wid = blockIdx.x * 4 + (threadIdx.x >> 6);
    if (wid >= n) return;
    int lane = threadIdx.x & 63;
    float lam = lam_p[0];
    float erv = er[wid];
    int s0 = rowptr[wid], s1 = rowptr[wid + 1];
    float acc = 0.f, s = 0.f;
    for (int i = s0; i < s1; ++i) {
        int sn = src_s[i];
        float wgt = ew_s[i];
        float e = el[sn] + erv + lam * wgt;
        e = (e >= 0.f) ? e : NEG_SLOPE * e;
        float p = __expf(e);
        acc = fmaf(p, ft[(size_t)sn * 64 + lane], acc);
        s += p;
    }
    float inv = (s > 0.f) ? 1.f / s : 0.f;
    float v = acc * inv;
    out[(size_t)wid * 64 + lane] = v;
    out[(size_t)n * 64 + (size_t)wid * 64 + lane] = v;
}

// ---------------- launch ----------------

extern "C" void kernel_launch(void* const* d_in, const int* in_sizes, int n_in,
                              void* d_out, int out_size, void* d_ws, size_t ws_size,
                              hipStream_t stream) {
    const float* features = (const float*)d_in[0];
    const float* edge_weight = (const float*)d_in[1];
    const int* src = (const int*)d_in[2];
    const int* dst = (const int*)d_in[3];
    const float* W0 = (const float*)d_in[4];
    const float* al0 = (const float*)d_in[5];
    const float* ar0 = (const float*)d_in[6];
    const float* lam0 = (const float*)d_in[7];
    const float* W1 = (const float*)d_in[8];
    const float* al1 = (const float*)d_in[9];
    const float* ar1 = (const float*)d_in[10];
    const float* lam1 = (const float*)d_in[11];
    const float* W2 = (const float*)d_in[12];
    const float* al2 = (const float*)d_in[13];
    const float* ar2 = (const float*)d_in[14];
    const float* lam2 = (const float*)d_in[15];
    const float* g0 = (const float*)d_in[16];
    const float* b0 = (const float*)d_in[17];
    const float* g1 = (const float*)d_in[18];
    const float* b1 = (const float*)d_in[19];

    const int N = in_sizes[0] / 128;
    const int E = in_sizes[1];

    char* w = (char*)d_ws;
    size_t o = 0;
    auto carve = [&](size_t bytes) {
        char* p = w + o;
        o += (bytes + 255) & ~(size_t)255;
        return p;
    };
    int* counts = (int*)carve((size_t)N * 4);        // doubles as scatter cursor
    int* rowptr = (int*)carve((size_t)(N + 1) * 4);
    int* bsum = (int*)carve(256 * 4);
    int* src_s = (int*)carve((size_t)E * 4);
    float* ew_s = (float*)carve((size_t)E * 4);
    float* ft = (float*)carve((size_t)N * 128 * 4);
    float* el = (float*)carve((size_t)N * 4 * 4);
    float* er = (float*)carve((size_t)N * 4 * 4);
    float* h1 = (float*)carve((size_t)N * 128 * 4);
    float* h2 = (float*)carve((size_t)N * 128 * 4);

    const int nscan = (N + 255) / 256;            // blocks for scan passes (<=256)

    // CSR by dst (shared across the 3 layers)
    hipMemsetAsync(counts, 0, (size_t)N * 4, stream);
    hist_kernel<<<(E + 255) / 256, 256, 0, stream>>>(dst, counts, E);
    scan1_kernel<<<nscan, 256, 0, stream>>>(counts, bsum, N);
    scan2_kernel<<<1, 256, 0, stream>>>(bsum, nscan);
    scan3_kernel<<<(N + 1 + 255) / 256, 256, 0, stream>>>(counts, bsum, rowptr, N, E);
    scatter_kernel<<<(E + 255) / 256, 256, 0, stream>>>(src, dst, edge_weight, counts,
                                                        src_s, ew_s, E);

    // Layer 0
    gemm_kernel<128><<<(N + 31) / 32, 256, 0, stream>>>(features, W0, ft, N);
    elr_kernel<<<(N * 4 + 255) / 256, 256, 0, stream>>>(ft, al0, ar0, el, er, N, 4, 32, 128);
    gat_agg_ln<<<(N + 3) / 4, 256, 0, stream>>>(rowptr, src_s, ew_s, ft, el, er, lam0,
                                                g0, b0, features, h1, N);
    // Layer 1
    gemm_kernel<128><<<(N + 31) / 32, 256, 0, stream>>>(h1, W1, ft, N);
    elr_kernel<<<(N * 4 + 255) / 256, 256, 0, stream>>>(ft, al1, ar1, el, er, N, 4, 32, 128);
    gat_agg_ln<<<(N + 3) / 4, 256, 0, stream>>>(rowptr, src_s, ew_s, ft, el, er, lam1,
                                                g1, b1, h1, h2, N);
    // Layer 2
    gemm_kernel<64><<<(N + 31) / 32, 256, 0, stream>>>(h2, W2, ft, N);
    elr_kernel<<<(N + 255) / 256, 256, 0, stream>>>(ft, al2, ar2, el, er, N, 1, 64, 64);
    gat_agg_out<<<(N + 3) / 4, 256, 0, stream>>>(rowptr, src_s, ew_s, ft, el, er, lam2,
                                                 (float*)d_out, N);
}

// Round 4
// 539.820 us; speedup vs baseline: 2.0517x; 1.2025x over previous
//
#include <hip/hip_runtime.h>

#define NEG_SLOPE 0.2f
#define LN_EPS 1e-5f

// ---------------- CSR build ----------------

__global__ void hist_kernel(const int* __restrict__ dst, int* __restrict__ counts, int E) {
    int i = blockIdx.x * blockDim.x + threadIdx.x;
    if (i < E) atomicAdd(&counts[dst[i]], 1);
}

// Hierarchical scan, pass 1: per-block sums of counts (256 elems/block).
__global__ __launch_bounds__(256) void scan1_kernel(const int* __restrict__ counts,
                                                    int* __restrict__ bsum, int n) {
    __shared__ int lds[256];
    int t = threadIdx.x;
    int i = blockIdx.x * 256 + t;
    lds[t] = (i < n) ? counts[i] : 0;
    __syncthreads();
    for (int off = 128; off > 0; off >>= 1) {
        int v = (t < off) ? lds[t + off] : 0;
        __syncthreads();
        if (t < off) lds[t] += v;
        __syncthreads();
    }
    if (t == 0) bsum[blockIdx.x] = lds[0];
}

// Pass 2: single tiny block scans the (<=256) block sums -> exclusive.
__global__ __launch_bounds__(256) void scan2_kernel(int* __restrict__ bsum, int nblocks) {
    __shared__ int lds[256];
    int t = threadIdx.x;
    int v0 = (t < nblocks) ? bsum[t] : 0;
    lds[t] = v0;
    __syncthreads();
    for (int off = 1; off < 256; off <<= 1) {
        int v = (t >= off) ? lds[t - off] : 0;
        __syncthreads();
        lds[t] += v;
        __syncthreads();
    }
    if (t < nblocks) bsum[t] = lds[t] - v0;  // exclusive
}

// Pass 3: per-block LDS scan + block offset -> rowptr + scatter cursor.
__global__ __launch_bounds__(256) void scan3_kernel(int* __restrict__ counts,
                                                    const int* __restrict__ bsum,
                                                    int* __restrict__ rowptr, int n, int E) {
    __shared__ int lds[256];
    int t = threadIdx.x;
    int i = blockIdx.x * 256 + t;
    int c = (i < n) ? counts[i] : 0;
    lds[t] = c;
    __syncthreads();
    for (int off = 1; off < 256; off <<= 1) {
        int v = (t >= off) ? lds[t - off] : 0;
        __syncthreads();
        lds[t] += v;
        __syncthreads();
    }
    int ex = bsum[blockIdx.x] + lds[t] - c;  // exclusive prefix
    if (i < n) {
        rowptr[i] = ex;
        counts[i] = ex;  // cursor for scatter
    }
    if (i == n) rowptr[n] = E;
}

// Packs (src, bitcast(ew)) into int2 so the agg loop does one 8B load per edge.
__global__ void scatter_kernel(const int* __restrict__ src, const int* __restrict__ dst,
                               const float* __restrict__ ew, int* __restrict__ cursor,
                               int2* __restrict__ edge_s, int E) {
    int i = blockIdx.x * blockDim.x + threadIdx.x;
    if (i < E) {
        int p = atomicAdd(&cursor[dst[i]], 1);
        edge_s[p] = make_int2(src[i], __float_as_int(ew[i]));
    }
}

// ---------------- GEMM: C[n,K] = A[n,128] @ W[128,K] ----------------
// 32 rows x K cols per block; W staged in LDS in 32-k chunks (16 KB for K=128)
// to keep occupancy high and VGPRs < 128 (R0 regression: full-W 64 KB LDS +
// fully-unrolled staging spilled ~870 MB of scratch per dispatch).

template <int K>
__global__ __launch_bounds__(256) void gemm_kernel(const float* __restrict__ A,
                                                   const float* __restrict__ W,
                                                   float* __restrict__ C, int n) {
    constexpr int CG = K / 4;          // float4 col-groups per row
    constexpr int RPT = CG / 8;        // rows per thread (K=128 -> 4, K=64 -> 2)
    constexpr int CHUNK_V = 32 * CG;   // float4s per 32-k chunk of W
    __shared__ float4 Wl4[CHUNK_V];

    int t = threadIdx.x;
    int cg = t % CG, rg = t / CG;
    int row0 = blockIdx.x * 32 + rg * RPT;
    const float4* A4 = (const float4*)A;
    const float4* W4 = (const float4*)W;

    float acc[RPT][4] = {};
    for (int c = 0; c < 4; ++c) {   // 4 chunks of 32 k-values
        __syncthreads();
        #pragma unroll
        for (int i = 0; i < CHUNK_V / 256; ++i)
            Wl4[t + i * 256] = W4[c * CHUNK_V + t + i * 256];
        __syncthreads();
        #pragma unroll 2
        for (int k4 = 0; k4 < 8; ++k4) {
            float4 a[RPT];
            #pragma unroll
            for (int r = 0; r < RPT; ++r) {
                int row = row0 + r;
                a[r] = (row < n) ? A4[(size_t)row * 32 + c * 8 + k4]
                                 : make_float4(0.f, 0.f, 0.f, 0.f);
            }
            #pragma unroll
            for (int j = 0; j < 4; ++j) {
                float4 wv = Wl4[(k4 * 4 + j) * CG + cg];
                #pragma unroll
                for (int r = 0; r < RPT; ++r) {
                    float av = (j == 0) ? a[r].x : (j == 1) ? a[r].y : (j == 2) ? a[r].z : a[r].w;
                    acc[r][0] = fmaf(av, wv.x, acc[r][0]);
                    acc[r][1] = fmaf(av, wv.y, acc[r][1]);
                    acc[r][2] = fmaf(av, wv.z, acc[r][2]);
                    acc[r][3] = fmaf(av, wv.w, acc[r][3]);
                }
            }
        }
    }
    #pragma unroll
    for (int r = 0; r < RPT; ++r) {
        int row = row0 + r;
        if (row < n)
            *((float4*)&C[(size_t)row * K + cg * 4]) =
                make_float4(acc[r][0], acc[r][1], acc[r][2], acc[r][3]);
    }
}

// ---------------- el/er: [n,H] attention logit halves ----------------

__global__ void elr_kernel(const float* __restrict__ ft, const float* __restrict__ al,
                           const float* __restrict__ ar, float* __restrict__ el,
                           float* __restrict__ er, int n, int H, int D, int HD) {
    int i = blockIdx.x * blockDim.x + threadIdx.x;
    if (i >= n * H) return;
    int node = i / H, h = i - node * H;
    const float4* f4 = (const float4*)(ft + (size_t)node * HD + h * D);
    const float4* a4 = (const float4*)(al + h * D);
    const float4* r4 = (const float4*)(ar + h * D);
    float sl = 0.f, sr = 0.f;
    for (int d = 0; d < D / 4; ++d) {
        float4 f = f4[d], a = a4[d], r = r4[d];
        sl += f.x * a.x + f.y * a.y + f.z * a.z + f.w * a.w;
        sr += f.x * r.x + f.y * r.y + f.z * r.z + f.w * r.w;
    }
    el[i] = sl;
    er[i] = sr;
}

// ---------------- fused GAT aggregate + ELU + LayerNorm + residual ----------------
// One wave per dst node; HD=128 as float2/lane; head = lane/16.
// Edge loop batched x4 (+unroll 2) so up to 8 ft-row gathers are in flight —
// R3 profile showed the serial per-edge chain was latency-bound (VALU 37%,
// HBM 30%).

__global__ __launch_bounds__(256) void gat_agg_ln(
    const int* __restrict__ rowptr, const int2* __restrict__ edge_s,
    const float* __restrict__ ft, const float* __restrict__ el,
    const float* __restrict__ er, const float* __restrict__ lam_p,
    const float* __restrict__ g, const float* __restrict__ b,
    const float* __restrict__ prev, float* __restrict__ out, int n) {
    int wid = blockIdx.x * 4 + (threadIdx.x >> 6);
    if (wid >= n) return;
    int lane = threadIdx.x & 63;
    int head = lane >> 4;
    float lam = lam_p[0];
    float erv = er[wid * 4 + head];
    int s0 = rowptr[wid], s1 = rowptr[wid + 1];
    const float2* ft2 = (const float2*)ft;
    float ax = 0.f, ay = 0.f, s = 0.f;

    int i = s0;
    #pragma unroll 2
    for (; i + 4 <= s1; i += 4) {
        int2 e0 = edge_s[i], e1 = edge_s[i + 1], e2 = edge_s[i + 2], e3 = edge_s[i + 3];
        float2 f0 = ft2[(size_t)e0.x * 64 + lane];
        float2 f1 = ft2[(size_t)e1.x * 64 + lane];
        float2 f2 = ft2[(size_t)e2.x * 64 + lane];
        float2 f3 = ft2[(size_t)e3.x * 64 + lane];
        float l0 = el[e0.x * 4 + head];
        float l1 = el[e1.x * 4 + head];
        float l2 = el[e2.x * 4 + head];
        float l3 = el[e3.x * 4 + head];
        float v0 = l0 + erv + lam * __int_as_float(e0.y);
        float v1 = l1 + erv + lam * __int_as_float(e1.y);
        float v2 = l2 + erv + lam * __int_as_float(e2.y);
        float v3 = l3 + erv + lam * __int_as_float(e3.y);
        v0 = (v0 >= 0.f) ? v0 : NEG_SLOPE * v0;
        v1 = (v1 >= 0.f) ? v1 : NEG_SLOPE * v1;
        v2 = (v2 >= 0.f) ? v2 : NEG_SLOPE * v2;
        v3 = (v3 >= 0.f) ? v3 : NEG_SLOPE * v3;
        float p0 = __expf(v0), p1 = __expf(v1), p2 = __expf(v2), p3 = __expf(v3);
        ax = fmaf(p0, f0.x, ax); ay = fmaf(p0, f0.y, ay);
        ax = fmaf(p1, f1.x, ax); ay = fmaf(p1, f1.y, ay);
        ax = fmaf(p2, f2.x, ax); ay = fmaf(p2, f2.y, ay);
        ax = fmaf(p3, f3.x, ax); ay = fmaf(p3, f3.y, ay);
        s += (p0 + p1) + (p2 + p3);
    }
    for (; i < s1; ++i) {
        int2 e = edge_s[i];
        float2 f = ft2[(size_t)e.x * 64 + lane];
        float v = el[e.x * 4 + head] + erv + lam * __int_as_float(e.y);
        v = (v >= 0.f) ? v : NEG_SLOPE * v;
        float p = __expf(v);
        ax = fmaf(p, f.x, ax);
        ay = fmaf(p, f.y, ay);
        s += p;
    }

    float inv = (s > 0.f) ? 1.f / s : 0.f;
    float x0 = ax * inv, x1 = ay * inv;
    // ELU
    x0 = (x0 > 0.f) ? x0 : expm1f(x0);
    x1 = (x1 > 0.f) ? x1 : expm1f(x1);
    // LayerNorm over 128 dims spread across 64 lanes
    float sum = x0 + x1, sq = x0 * x0 + x1 * x1;
    #pragma unroll
    for (int off = 32; off > 0; off >>= 1) {
        sum += __shfl_xor(sum, off, 64);
        sq += __shfl_xor(sq, off, 64);
    }
    float mu = sum * (1.f / 128.f);
    float var = sq * (1.f / 128.f) - mu * mu;
    float rs = rsqrtf(var + LN_EPS);
    float2 gv = ((const float2*)g)[lane];
    float2 bv = ((const float2*)b)[lane];
    float2 pv = ((const float2*)prev)[(size_t)wid * 64 + lane];
    float2 y;
    y.x = (x0 - mu) * rs * gv.x + bv.x + pv.x;
    y.y = (x1 - mu) * rs * gv.y + bv.y + pv.y;
    ((float2*)out)[(size_t)wid * 64 + lane] = y;
}

// Layer 2: H=1, OUT=64, no epilogue; writes both tuple halves.
__global__ __launch_bounds__(256) void gat_agg_out(
    const int* __restrict__ rowptr, const int2* __restrict__ edge_s,
    const float* __restrict__ ft, const float* __restrict__ el,
    const float* __restrict__ er, const float* __restrict__ lam_p,
    float* __restrict__ out, int n) {
    int wid = blockIdx.x * 4 + (threadIdx.x >> 6);
    if (wid >= n) return;
    int lane = threadIdx.x & 63;
    float lam = lam_p[0];
    float erv = er[wid];
    int s0 = rowptr[wid], s1 = rowptr[wid + 1];
    float acc = 0.f, s = 0.f;

    int i = s0;
    #pragma unroll 2
    for (; i + 4 <= s1; i += 4) {
        int2 e0 = edge_s[i], e1 = edge_s[i + 1], e2 = edge_s[i + 2], e3 = edge_s[i + 3];
        float f0 = ft[(size_t)e0.x * 64 + lane];
        float f1 = ft[(size_t)e1.x * 64 + lane];
        float f2 = ft[(size_t)e2.x * 64 + lane];
        float f3 = ft[(size_t)e3.x * 64 + lane];
        float l0 = el[e0.x], l1 = el[e1.x], l2 = el[e2.x], l3 = el[e3.x];
        float v0 = l0 + erv + lam * __int_as_float(e0.y);
        float v1 = l1 + erv + lam * __int_as_float(e1.y);
        float v2 = l2 + erv + lam * __int_as_float(e2.y);
        float v3 = l3 + erv + lam * __int_as_float(e3.y);
        v0 = (v0 >= 0.f) ? v0 : NEG_SLOPE * v0;
        v1 = (v1 >= 0.f) ? v1 : NEG_SLOPE * v1;
        v2 = (v2 >= 0.f) ? v2 : NEG_SLOPE * v2;
        v3 = (v3 >= 0.f) ? v3 : NEG_SLOPE * v3;
        float p0 = __expf(v0), p1 = __expf(v1), p2 = __expf(v2), p3 = __expf(v3);
        acc = fmaf(p0, f0, acc);
        acc = fmaf(p1, f1, acc);
        acc = fmaf(p2, f2, acc);
        acc = fmaf(p3, f3, acc);
        s += (p0 + p1) + (p2 + p3);
    }
    for (; i < s1; ++i) {
        int2 e = edge_s[i];
        float f = ft[(size_t)e.x * 64 + lane];
        float v = el[e.x] + erv + lam * __int_as_float(e.y);
        v = (v >= 0.f) ? v : NEG_SLOPE * v;
        float p = __expf(v);
        acc = fmaf(p, f, acc);
        s += p;
    }

    float inv = (s > 0.f) ? 1.f / s : 0.f;
    float v = acc * inv;
    out[(size_t)wid * 64 + lane] = v;
    out[(size_t)n * 64 + (size_t)wid * 64 + lane] = v;
}

// ---------------- launch ----------------

extern "C" void kernel_launch(void* const* d_in, const int* in_sizes, int n_in,
                              void* d_out, int out_size, void* d_ws, size_t ws_size,
                              hipStream_t stream) {
    const float* features = (const float*)d_in[0];
    const float* edge_weight = (const float*)d_in[1];
    const int* src = (const int*)d_in[2];
    const int* dst = (const int*)d_in[3];
    const float* W0 = (const float*)d_in[4];
    const float* al0 = (const float*)d_in[5];
    const float* ar0 = (const float*)d_in[6];
    const float* lam0 = (const float*)d_in[7];
    const float* W1 = (const float*)d_in[8];
    const float* al1 = (const float*)d_in[9];
    const float* ar1 = (const float*)d_in[10];
    const float* lam1 = (const float*)d_in[11];
    const float* W2 = (const float*)d_in[12];
    const float* al2 = (const float*)d_in[13];
    const float* ar2 = (const float*)d_in[14];
    const float* lam2 = (const float*)d_in[15];
    const float* g0 = (const float*)d_in[16];
    const float* b0 = (const float*)d_in[17];
    const float* g1 = (const float*)d_in[18];
    const float* b1 = (const float*)d_in[19];

    const int N = in_sizes[0] / 128;
    const int E = in_sizes[1];

    char* w = (char*)d_ws;
    size_t o = 0;
    auto carve = [&](size_t bytes) {
        char* p = w + o;
        o += (bytes + 255) & ~(size_t)255;
        return p;
    };
    int* counts = (int*)carve((size_t)N * 4);        // doubles as scatter cursor
    int* rowptr = (int*)carve((size_t)(N + 1) * 4);
    int* bsum = (int*)carve(256 * 4);
    int2* edge_s = (int2*)carve((size_t)E * 8);
    float* ft = (float*)carve((size_t)N * 128 * 4);
    float* el = (float*)carve((size_t)N * 4 * 4);
    float* er = (float*)carve((size_t)N * 4 * 4);
    float* h1 = (float*)carve((size_t)N * 128 * 4);
    float* h2 = (float*)carve((size_t)N * 128 * 4);

    const int nscan = (N + 255) / 256;            // blocks for scan passes (<=256)

    // CSR by dst (shared across the 3 layers)
    hipMemsetAsync(counts, 0, (size_t)N * 4, stream);
    hist_kernel<<<(E + 255) / 256, 256, 0, stream>>>(dst, counts, E);
    scan1_kernel<<<nscan, 256, 0, stream>>>(counts, bsum, N);
    scan2_kernel<<<1, 256, 0, stream>>>(bsum, nscan);
    scan3_kernel<<<(N + 1 + 255) / 256, 256, 0, stream>>>(counts, bsum, rowptr, N, E);
    scatter_kernel<<<(E + 255) / 256, 256, 0, stream>>>(src, dst, edge_weight, counts,
                                                        edge_s, E);

    // Layer 0
    gemm_kernel<128><<<(N + 31) / 32, 256, 0, stream>>>(features, W0, ft, N);
    elr_kernel<<<(N * 4 + 255) / 256, 256, 0, stream>>>(ft, al0, ar0, el, er, N, 4, 32, 128);
    gat_agg_ln<<<(N + 3) / 4, 256, 0, stream>>>(rowptr, edge_s, ft, el, er, lam0,
                                                g0, b0, features, h1, N);
    // Layer 1
    gemm_kernel<128><<<(N + 31) / 32, 256, 0, stream>>>(h1, W1, ft, N);
    elr_kernel<<<(N * 4 + 255) / 256, 256, 0, stream>>>(ft, al1, ar1, el, er, N, 4, 32, 128);
    gat_agg_ln<<<(N + 3) / 4, 256, 0, stream>>>(rowptr, edge_s, ft, el, er, lam1,
                                                g1, b1, h1, h2, N);
    // Layer 2
    gemm_kernel<64><<<(N + 31) / 32, 256, 0, stream>>>(h2, W2, ft, N);
    elr_kernel<<<(N + 255) / 256, 256, 0, stream>>>(ft, al2, ar2, el, er, N, 1, 64, 64);
    gat_agg_out<<<(N + 3) / 4, 256, 0, stream>>>(rowptr, edge_s, ft, el, er, lam2,
                                                 (float*)d_out, N);
}

// Round 5
// 439.839 us; speedup vs baseline: 2.5180x; 1.2273x over previous
//
#include <hip/hip_runtime.h>

#define NEG_SLOPE 0.2f
#define LN_EPS 1e-5f

typedef __attribute__((ext_vector_type(8))) short bf16x8;
typedef __attribute__((ext_vector_type(4))) float f32x4;

__device__ inline unsigned short f2bf(float f) {
    unsigned u = __float_as_uint(f);
    unsigned r = u + 0x7FFFu + ((u >> 16) & 1u);   // round-to-nearest-even
    return (unsigned short)(r >> 16);
}

// ---------------- CSR build ----------------

__global__ void hist_kernel(const int* __restrict__ dst, int* __restrict__ counts, int E) {
    int i = blockIdx.x * blockDim.x + threadIdx.x;
    if (i < E) atomicAdd(&counts[dst[i]], 1);
}

__global__ __launch_bounds__(256) void scan1_kernel(const int* __restrict__ counts,
                                                    int* __restrict__ bsum, int n) {
    __shared__ int lds[256];
    int t = threadIdx.x;
    int i = blockIdx.x * 256 + t;
    lds[t] = (i < n) ? counts[i] : 0;
    __syncthreads();
    for (int off = 128; off > 0; off >>= 1) {
        int v = (t < off) ? lds[t + off] : 0;
        __syncthreads();
        if (t < off) lds[t] += v;
        __syncthreads();
    }
    if (t == 0) bsum[blockIdx.x] = lds[0];
}

__global__ __launch_bounds__(256) void scan2_kernel(int* __restrict__ bsum, int nblocks) {
    __shared__ int lds[256];
    int t = threadIdx.x;
    int v0 = (t < nblocks) ? bsum[t] : 0;
    lds[t] = v0;
    __syncthreads();
    for (int off = 1; off < 256; off <<= 1) {
        int v = (t >= off) ? lds[t - off] : 0;
        __syncthreads();
        lds[t] += v;
        __syncthreads();
    }
    if (t < nblocks) bsum[t] = lds[t] - v0;  // exclusive
}

__global__ __launch_bounds__(256) void scan3_kernel(int* __restrict__ counts,
                                                    const int* __restrict__ bsum,
                                                    int* __restrict__ rowptr, int n, int E) {
    __shared__ int lds[256];
    int t = threadIdx.x;
    int i = blockIdx.x * 256 + t;
    int c = (i < n) ? counts[i] : 0;
    lds[t] = c;
    __syncthreads();
    for (int off = 1; off < 256; off <<= 1) {
        int v = (t >= off) ? lds[t - off] : 0;
        __syncthreads();
        lds[t] += v;
        __syncthreads();
    }
    int ex = bsum[blockIdx.x] + lds[t] - c;  // exclusive prefix
    if (i < n) {
        rowptr[i] = ex;
        counts[i] = ex;  // cursor for scatter
    }
    if (i == n) rowptr[n] = E;
}

// Packs (src, bitcast(ew)) into int2 so the agg loop does one 8B load per edge.
__global__ void scatter_kernel(const int* __restrict__ src, const int* __restrict__ dst,
                               const float* __restrict__ ew, int* __restrict__ cursor,
                               int2* __restrict__ edge_s, int E) {
    int i = blockIdx.x * blockDim.x + threadIdx.x;
    if (i < E) {
        int p = atomicAdd(&cursor[dst[i]], 1);
        edge_s[p] = make_int2(src[i], __float_as_int(ew[i]));
    }
}

// ---------------- W transpose-cast: Wt[n][k] bf16 <- W[k][n] fp32 ----------------
// Tiny (<=16K elems), once per layer; gives contiguous-in-k B-fragments.

__global__ void wcast_kernel(const float* __restrict__ W, unsigned short* __restrict__ Wt,
                             int ncols) {
    int n = blockIdx.x;        // output row (0..ncols-1)
    int k = threadIdx.x;       // 0..127
    Wt[n * 128 + k] = f2bf(W[k * ncols + n]);
}

// ---------------- MFMA GEMM: C[n, NT*16] = A[n,128] @ W[128, NT*16] ----------------
// 64 rows/block, 4 waves; A staged fp32->bf16 into LDS (pad 8 bf16 -> 4-bank
// row stride, 2-way = free); Wt staged whole. Verified gfx950 layouts:
// A/B frag: outer = lane&15, k = (lane>>4)*8 + j; C/D: col=lane&15,
// row=(lane>>4)*4+reg. One barrier per block.

template <int NT>
__global__ __launch_bounds__(256) void gemm_mfma(const float* __restrict__ A,
                                                 const unsigned short* __restrict__ Wt,
                                                 float* __restrict__ C, int n) {
    constexpr int LDA = 136;  // bf16 elems per LDS row (128 + 8 pad)
    __shared__ unsigned short As[64 * LDA];
    __shared__ unsigned short Ws[NT * 16 * LDA];
    int t = threadIdx.x;
    int row0 = blockIdx.x * 64;

    // stage A tile (fp32 global -> bf16 LDS), coalesced
    const float4* A4 = (const float4*)A;
    #pragma unroll
    for (int j = 0; j < 8; ++j) {
        int idx = t + j * 256;  // float4 index within 64x128 tile
        int r = idx >> 5;
        int c4 = idx & 31;
        int row = row0 + r;
        float4 v = (row < n) ? A4[(size_t)row * 32 + c4] : make_float4(0.f, 0.f, 0.f, 0.f);
        unsigned p0 = (unsigned)f2bf(v.x) | ((unsigned)f2bf(v.y) << 16);
        unsigned p1 = (unsigned)f2bf(v.z) | ((unsigned)f2bf(v.w) << 16);
        *(uint2*)&As[r * LDA + c4 * 4] = make_uint2(p0, p1);
    }
    // stage Wt (bf16 global [NT*16][128] -> LDS padded)
    const uint4* Wg = (const uint4*)Wt;  // 16 B = 8 bf16
    #pragma unroll
    for (int j = 0; j < NT; ++j) {
        int idx = t + j * 256;  // 8-bf16 chunk index
        int r = idx >> 4;
        int c8 = idx & 15;
        *(uint4*)&Ws[r * LDA + c8 * 8] = Wg[idx];
    }
    __syncthreads();

    int w = t >> 6, lane = t & 63;
    int m = lane & 15, q = lane >> 4;
    f32x4 acc[NT] = {};
    const unsigned short* ap = &As[(w * 16 + m) * LDA + q * 8];
    #pragma unroll
    for (int kk = 0; kk < 4; ++kk) {
        bf16x8 a = *(const bf16x8*)(ap + kk * 32);
        #pragma unroll
        for (int nt = 0; nt < NT; ++nt) {
            bf16x8 b = *(const bf16x8*)&Ws[(nt * 16 + m) * LDA + kk * 32 + q * 8];
            acc[nt] = __builtin_amdgcn_mfma_f32_16x16x32_bf16(a, b, acc[nt], 0, 0, 0);
        }
    }
    int orow = row0 + w * 16 + q * 4;
    #pragma unroll
    for (int nt = 0; nt < NT; ++nt) {
        #pragma unroll
        for (int r = 0; r < 4; ++r) {
            int row = orow + r;
            if (row < n) C[(size_t)row * (NT * 16) + nt * 16 + m] = acc[nt][r];
        }
    }
}

// ---------------- el/er: [n,H] attention logit halves ----------------

__global__ void elr_kernel(const float* __restrict__ ft, const float* __restrict__ al,
                           const float* __restrict__ ar, float* __restrict__ el,
                           float* __restrict__ er, int n, int H, int D, int HD) {
    int i = blockIdx.x * blockDim.x + threadIdx.x;
    if (i >= n * H) return;
    int node = i / H, h = i - node * H;
    const float4* f4 = (const float4*)(ft + (size_t)node * HD + h * D);
    const float4* a4 = (const float4*)(al + h * D);
    const float4* r4 = (const float4*)(ar + h * D);
    float sl = 0.f, sr = 0.f;
    for (int d = 0; d < D / 4; ++d) {
        float4 f = f4[d], a = a4[d], r = r4[d];
        sl += f.x * a.x + f.y * a.y + f.z * a.z + f.w * a.w;
        sr += f.x * r.x + f.y * r.y + f.z * r.z + f.w * r.w;
    }
    el[i] = sl;
    er[i] = sr;
}

// ---------------- fused GAT aggregate + ELU + LayerNorm + residual ----------------
// One wave per dst node; HD=128 as float2/lane; head = lane/16.
// Edge loop batched x4 (+unroll 2): up to 8 ft-row gathers in flight.

__global__ __launch_bounds__(256) void gat_agg_ln(
    const int* __restrict__ rowptr, const int2* __restrict__ edge_s,
    const float* __restrict__ ft, const float* __restrict__ el,
    const float* __restrict__ er, const float* __restrict__ lam_p,
    const float* __restrict__ g, const float* __restrict__ b,
    const float* __restrict__ prev, float* __restrict__ out, int n) {
    int wid = blockIdx.x * 4 + (threadIdx.x >> 6);
    if (wid >= n) return;
    int lane = threadIdx.x & 63;
    int head = lane >> 4;
    float lam = lam_p[0];
    float erv = er[wid * 4 + head];
    int s0 = rowptr[wid], s1 = rowptr[wid + 1];
    const float2* ft2 = (const float2*)ft;
    float ax = 0.f, ay = 0.f, s = 0.f;

    int i = s0;
    #pragma unroll 2
    for (; i + 4 <= s1; i += 4) {
        int2 e0 = edge_s[i], e1 = edge_s[i + 1], e2 = edge_s[i + 2], e3 = edge_s[i + 3];
        float2 f0 = ft2[(size_t)e0.x * 64 + lane];
        float2 f1 = ft2[(size_t)e1.x * 64 + lane];
        float2 f2 = ft2[(size_t)e2.x * 64 + lane];
        float2 f3 = ft2[(size_t)e3.x * 64 + lane];
        float l0 = el[e0.x * 4 + head];
        float l1 = el[e1.x * 4 + head];
        float l2 = el[e2.x * 4 + head];
        float l3 = el[e3.x * 4 + head];
        float v0 = l0 + erv + lam * __int_as_float(e0.y);
        float v1 = l1 + erv + lam * __int_as_float(e1.y);
        float v2 = l2 + erv + lam * __int_as_float(e2.y);
        float v3 = l3 + erv + lam * __int_as_float(e3.y);
        v0 = (v0 >= 0.f) ? v0 : NEG_SLOPE * v0;
        v1 = (v1 >= 0.f) ? v1 : NEG_SLOPE * v1;
        v2 = (v2 >= 0.f) ? v2 : NEG_SLOPE * v2;
        v3 = (v3 >= 0.f) ? v3 : NEG_SLOPE * v3;
        float p0 = __expf(v0), p1 = __expf(v1), p2 = __expf(v2), p3 = __expf(v3);
        ax = fmaf(p0, f0.x, ax); ay = fmaf(p0, f0.y, ay);
        ax = fmaf(p1, f1.x, ax); ay = fmaf(p1, f1.y, ay);
        ax = fmaf(p2, f2.x, ax); ay = fmaf(p2, f2.y, ay);
        ax = fmaf(p3, f3.x, ax); ay = fmaf(p3, f3.y, ay);
        s += (p0 + p1) + (p2 + p3);
    }
    for (; i < s1; ++i) {
        int2 e = edge_s[i];
        float2 f = ft2[(size_t)e.x * 64 + lane];
        float v = el[e.x * 4 + head] + erv + lam * __int_as_float(e.y);
        v = (v >= 0.f) ? v : NEG_SLOPE * v;
        float p = __expf(v);
        ax = fmaf(p, f.x, ax);
        ay = fmaf(p, f.y, ay);
        s += p;
    }

    float inv = (s > 0.f) ? 1.f / s : 0.f;
    float x0 = ax * inv, x1 = ay * inv;
    x0 = (x0 > 0.f) ? x0 : expm1f(x0);
    x1 = (x1 > 0.f) ? x1 : expm1f(x1);
    float sum = x0 + x1, sq = x0 * x0 + x1 * x1;
    #pragma unroll
    for (int off = 32; off > 0; off >>= 1) {
        sum += __shfl_xor(sum, off, 64);
        sq += __shfl_xor(sq, off, 64);
    }
    float mu = sum * (1.f / 128.f);
    float var = sq * (1.f / 128.f) - mu * mu;
    float rs = rsqrtf(var + LN_EPS);
    float2 gv = ((const float2*)g)[lane];
    float2 bv = ((const float2*)b)[lane];
    float2 pv = ((const float2*)prev)[(size_t)wid * 64 + lane];
    float2 y;
    y.x = (x0 - mu) * rs * gv.x + bv.x + pv.x;
    y.y = (x1 - mu) * rs * gv.y + bv.y + pv.y;
    ((float2*)out)[(size_t)wid * 64 + lane] = y;
}

// Layer 2: H=1, OUT=64, no epilogue; writes both tuple halves.
__global__ __launch_bounds__(256) void gat_agg_out(
    const int* __restrict__ rowptr, const int2* __restrict__ edge_s,
    const float* __restrict__ ft, const float* __restrict__ el,
    const float* __restrict__ er, const float* __restrict__ lam_p,
    float* __restrict__ out, int n) {
    int wid = blockIdx.x * 4 + (threadIdx.x >> 6);
    if (wid >= n) return;
    int lane = threadIdx.x & 63;
    float lam = lam_p[0];
    float erv = er[wid];
    int s0 = rowptr[wid], s1 = rowptr[wid + 1];
    float acc = 0.f, s = 0.f;

    int i = s0;
    #pragma unroll 2
    for (; i + 4 <= s1; i += 4) {
        int2 e0 = edge_s[i], e1 = edge_s[i + 1], e2 = edge_s[i + 2], e3 = edge_s[i + 3];
        float f0 = ft[(size_t)e0.x * 64 + lane];
        float f1 = ft[(size_t)e1.x * 64 + lane];
        float f2 = ft[(size_t)e2.x * 64 + lane];
        float f3 = ft[(size_t)e3.x * 64 + lane];
        float l0 = el[e0.x], l1 = el[e1.x], l2 = el[e2.x], l3 = el[e3.x];
        float v0 = l0 + erv + lam * __int_as_float(e0.y);
        float v1 = l1 + erv + lam * __int_as_float(e1.y);
        float v2 = l2 + erv + lam * __int_as_float(e2.y);
        float v3 = l3 + erv + lam * __int_as_float(e3.y);
        v0 = (v0 >= 0.f) ? v0 : NEG_SLOPE * v0;
        v1 = (v1 >= 0.f) ? v1 : NEG_SLOPE * v1;
        v2 = (v2 >= 0.f) ? v2 : NEG_SLOPE * v2;
        v3 = (v3 >= 0.f) ? v3 : NEG_SLOPE * v3;
        float p0 = __expf(v0), p1 = __expf(v1), p2 = __expf(v2), p3 = __expf(v3);
        acc = fmaf(p0, f0, acc);
        acc = fmaf(p1, f1, acc);
        acc = fmaf(p2, f2, acc);
        acc = fmaf(p3, f3, acc);
        s += (p0 + p1) + (p2 + p3);
    }
    for (; i < s1; ++i) {
        int2 e = edge_s[i];
        float f = ft[(size_t)e.x * 64 + lane];
        float v = el[e.x] + erv + lam * __int_as_float(e.y);
        v = (v >= 0.f) ? v : NEG_SLOPE * v;
        float p = __expf(v);
        acc = fmaf(p, f, acc);
        s += p;
    }

    float inv = (s > 0.f) ? 1.f / s : 0.f;
    float v = acc * inv;
    out[(size_t)wid * 64 + lane] = v;
    out[(size_t)n * 64 + (size_t)wid * 64 + lane] = v;
}

// ---------------- launch ----------------

extern "C" void kernel_launch(void* const* d_in, const int* in_sizes, int n_in,
                              void* d_out, int out_size, void* d_ws, size_t ws_size,
                              hipStream_t stream) {
    const float* features = (const float*)d_in[0];
    const float* edge_weight = (const float*)d_in[1];
    const int* src = (const int*)d_in[2];
    const int* dst = (const int*)d_in[3];
    const float* W0 = (const float*)d_in[4];
    const float* al0 = (const float*)d_in[5];
    const float* ar0 = (const float*)d_in[6];
    const float* lam0 = (const float*)d_in[7];
    const float* W1 = (const float*)d_in[8];
    const float* al1 = (const float*)d_in[9];
    const float* ar1 = (const float*)d_in[10];
    const float* lam1 = (const float*)d_in[11];
    const float* W2 = (const float*)d_in[12];
    const float* al2 = (const float*)d_in[13];
    const float* ar2 = (const float*)d_in[14];
    const float* lam2 = (const float*)d_in[15];
    const float* g0 = (const float*)d_in[16];
    const float* b0 = (const float*)d_in[17];
    const float* g1 = (const float*)d_in[18];
    const float* b1 = (const float*)d_in[19];

    const int N = in_sizes[0] / 128;
    const int E = in_sizes[1];

    char* w = (char*)d_ws;
    size_t o = 0;
    auto carve = [&](size_t bytes) {
        char* p = w + o;
        o += (bytes + 255) & ~(size_t)255;
        return p;
    };
    int* counts = (int*)carve((size_t)N * 4);        // doubles as scatter cursor
    int* rowptr = (int*)carve((size_t)(N + 1) * 4);
    int* bsum = (int*)carve(256 * 4);
    int2* edge_s = (int2*)carve((size_t)E * 8);
    float* ft = (float*)carve((size_t)N * 128 * 4);
    float* el = (float*)carve((size_t)N * 4 * 4);
    float* er = (float*)carve((size_t)N * 4 * 4);
    float* h1 = (float*)carve((size_t)N * 128 * 4);
    float* h2 = (float*)carve((size_t)N * 128 * 4);
    unsigned short* Wt0 = (unsigned short*)carve(128 * 128 * 2);
    unsigned short* Wt1 = (unsigned short*)carve(128 * 128 * 2);
    unsigned short* Wt2 = (unsigned short*)carve(64 * 128 * 2);

    const int nscan = (N + 255) / 256;
    const int ngemm = (N + 63) / 64;

    // CSR by dst (shared across the 3 layers)
    hipMemsetAsync(counts, 0, (size_t)N * 4, stream);
    hist_kernel<<<(E + 255) / 256, 256, 0, stream>>>(dst, counts, E);
    scan1_kernel<<<nscan, 256, 0, stream>>>(counts, bsum, N);
    scan2_kernel<<<1, 256, 0, stream>>>(bsum, nscan);
    scan3_kernel<<<(N + 1 + 255) / 256, 256, 0, stream>>>(counts, bsum, rowptr, N, E);
    scatter_kernel<<<(E + 255) / 256, 256, 0, stream>>>(src, dst, edge_weight, counts,
                                                        edge_s, E);
    // W transposes (tiny)
    wcast_kernel<<<128, 128, 0, stream>>>(W0, Wt0, 128);
    wcast_kernel<<<128, 128, 0, stream>>>(W1, Wt1, 128);
    wcast_kernel<<<64, 128, 0, stream>>>(W2, Wt2, 64);

    // Layer 0
    gemm_mfma<8><<<ngemm, 256, 0, stream>>>(features, Wt0, ft, N);
    elr_kernel<<<(N * 4 + 255) / 256, 256, 0, stream>>>(ft, al0, ar0, el, er, N, 4, 32, 128);
    gat_agg_ln<<<(N + 3) / 4, 256, 0, stream>>>(rowptr, edge_s, ft, el, er, lam0,
                                                g0, b0, features, h1, N);
    // Layer 1
    gemm_mfma<8><<<ngemm, 256, 0, stream>>>(h1, Wt1, ft, N);
    elr_kernel<<<(N * 4 + 255) / 256, 256, 0, stream>>>(ft, al1, ar1, el, er, N, 4, 32, 128);
    gat_agg_ln<<<(N + 3) / 4, 256, 0, stream>>>(rowptr, edge_s, ft, el, er, lam1,
                                                g1, b1, h1, h2, N);
    // Layer 2
    gemm_mfma<4><<<ngemm, 256, 0, stream>>>(h2, Wt2, ft, N);
    elr_kernel<<<(N + 255) / 256, 256, 0, stream>>>(ft, al2, ar2, el, er, N, 1, 64, 64);
    gat_agg_out<<<(N + 3) / 4, 256, 0, stream>>>(rowptr, edge_s, ft, el, er, lam2,
                                                 (float*)d_out, N);
}

// Round 6
// 362.915 us; speedup vs baseline: 3.0518x; 1.2120x over previous
//
#include <hip/hip_runtime.h>

#define NEG_SLOPE 0.2f
#define LN_EPS 1e-5f

typedef __attribute__((ext_vector_type(8))) short bf16x8;
typedef __attribute__((ext_vector_type(4))) float f32x4;

__device__ inline unsigned short f2bf(float f) {
    unsigned u = __float_as_uint(f);
    unsigned r = u + 0x7FFFu + ((u >> 16) & 1u);   // round-to-nearest-even
    return (unsigned short)(r >> 16);
}

// ---------------- CSR build ----------------

__global__ void hist_kernel(const int* __restrict__ dst, int* __restrict__ counts, int E) {
    int i = blockIdx.x * blockDim.x + threadIdx.x;
    if (i < E) atomicAdd(&counts[dst[i]], 1);
}

__global__ __launch_bounds__(256) void scan1_kernel(const int* __restrict__ counts,
                                                    int* __restrict__ bsum, int n) {
    __shared__ int lds[256];
    int t = threadIdx.x;
    int i = blockIdx.x * 256 + t;
    lds[t] = (i < n) ? counts[i] : 0;
    __syncthreads();
    for (int off = 128; off > 0; off >>= 1) {
        int v = (t < off) ? lds[t + off] : 0;
        __syncthreads();
        if (t < off) lds[t] += v;
        __syncthreads();
    }
    if (t == 0) bsum[blockIdx.x] = lds[0];
}

__global__ __launch_bounds__(256) void scan2_kernel(int* __restrict__ bsum, int nblocks) {
    __shared__ int lds[256];
    int t = threadIdx.x;
    int v0 = (t < nblocks) ? bsum[t] : 0;
    lds[t] = v0;
    __syncthreads();
    for (int off = 1; off < 256; off <<= 1) {
        int v = (t >= off) ? lds[t - off] : 0;
        __syncthreads();
        lds[t] += v;
        __syncthreads();
    }
    if (t < nblocks) bsum[t] = lds[t] - v0;  // exclusive
}

__global__ __launch_bounds__(256) void scan3_kernel(int* __restrict__ counts,
                                                    const int* __restrict__ bsum,
                                                    int* __restrict__ rowptr, int n, int E) {
    __shared__ int lds[256];
    int t = threadIdx.x;
    int i = blockIdx.x * 256 + t;
    int c = (i < n) ? counts[i] : 0;
    lds[t] = c;
    __syncthreads();
    for (int off = 1; off < 256; off <<= 1) {
        int v = (t >= off) ? lds[t - off] : 0;
        __syncthreads();
        lds[t] += v;
        __syncthreads();
    }
    int ex = bsum[blockIdx.x] + lds[t] - c;  // exclusive prefix
    if (i < n) {
        rowptr[i] = ex;
        counts[i] = ex;  // cursor for scatter
    }
    if (i == n) rowptr[n] = E;
}

// Packs (src, bitcast(ew)) into int2 so the agg loop does one 8B load per edge.
__global__ void scatter_kernel(const int* __restrict__ src, const int* __restrict__ dst,
                               const float* __restrict__ ew, int* __restrict__ cursor,
                               int2* __restrict__ edge_s, int E) {
    int i = blockIdx.x * blockDim.x + threadIdx.x;
    if (i < E) {
        int p = atomicAdd(&cursor[dst[i]], 1);
        edge_s[p] = make_int2(src[i], __float_as_int(ew[i]));
    }
}

// ---------------- W transpose-cast: Wt[n][k] bf16 <- W[k][n] fp32 ----------------

__global__ void wcast_kernel(const float* __restrict__ W, unsigned short* __restrict__ Wt,
                             int ncols) {
    int n = blockIdx.x;
    int k = threadIdx.x;
    Wt[n * 128 + k] = f2bf(W[k * ncols + n]);
}

// ---------------- MFMA GEMM + fused el/er + bf16 ft output ----------------
// C[n, NT*16] = A[n,128] @ W[128, NT*16]; 64 rows/block, 4 waves.
// Epilogue: each 16-lane quad holds 4 full rows of C -> compute
// el/er = per-head dots via in-lane fma + 4-step quad butterfly, and write
// ftb (bf16) for the edge-gather kernels (halves gather traffic; fp32 ft is
// never materialized). H heads, D = NT*16/H; head(col) = col/D = (nt*16)/D
// for m<16<=D.

template <int NT, int H>
__global__ __launch_bounds__(256) void gemm_mfma(const float* __restrict__ A,
                                                 const unsigned short* __restrict__ Wt,
                                                 const float* __restrict__ al,
                                                 const float* __restrict__ ar,
                                                 unsigned short* __restrict__ ftb,
                                                 float* __restrict__ el,
                                                 float* __restrict__ er, int n) {
    constexpr int LDA = 136;  // bf16 elems per LDS row (128 + 8 pad)
    constexpr int D = NT * 16 / H;
    __shared__ unsigned short As[64 * LDA];
    __shared__ unsigned short Ws[NT * 16 * LDA];
    int t = threadIdx.x;
    int row0 = blockIdx.x * 64;

    // stage A tile (fp32 global -> bf16 LDS), coalesced
    const float4* A4 = (const float4*)A;
    #pragma unroll
    for (int j = 0; j < 8; ++j) {
        int idx = t + j * 256;
        int r = idx >> 5;
        int c4 = idx & 31;
        int row = row0 + r;
        float4 v = (row < n) ? A4[(size_t)row * 32 + c4] : make_float4(0.f, 0.f, 0.f, 0.f);
        unsigned p0 = (unsigned)f2bf(v.x) | ((unsigned)f2bf(v.y) << 16);
        unsigned p1 = (unsigned)f2bf(v.z) | ((unsigned)f2bf(v.w) << 16);
        *(uint2*)&As[r * LDA + c4 * 4] = make_uint2(p0, p1);
    }
    // stage Wt (bf16 global [NT*16][128] -> LDS padded)
    const uint4* Wg = (const uint4*)Wt;
    #pragma unroll
    for (int j = 0; j < NT; ++j) {
        int idx = t + j * 256;
        int r = idx >> 4;
        int c8 = idx & 15;
        *(uint4*)&Ws[r * LDA + c8 * 8] = Wg[idx];
    }
    __syncthreads();

    int w = t >> 6, lane = t & 63;
    int m = lane & 15, q = lane >> 4;
    f32x4 acc[NT] = {};
    const unsigned short* ap = &As[(w * 16 + m) * LDA + q * 8];
    #pragma unroll
    for (int kk = 0; kk < 4; ++kk) {
        bf16x8 a = *(const bf16x8*)(ap + kk * 32);
        #pragma unroll
        for (int nt = 0; nt < NT; ++nt) {
            bf16x8 b = *(const bf16x8*)&Ws[(nt * 16 + m) * LDA + kk * 32 + q * 8];
            acc[nt] = __builtin_amdgcn_mfma_f32_16x16x32_bf16(a, b, acc[nt], 0, 0, 0);
        }
    }

    // per-thread attention-vector values for its columns (col = nt*16 + m)
    float alv[NT], arv[NT];
    #pragma unroll
    for (int nt = 0; nt < NT; ++nt) {
        alv[nt] = al[nt * 16 + m];
        arv[nt] = ar[nt * 16 + m];
    }

    int orow = row0 + w * 16 + q * 4;
    #pragma unroll
    for (int r = 0; r < 4; ++r) {
        int row = orow + r;
        float pl[H] = {}, pr[H] = {};
        #pragma unroll
        for (int nt = 0; nt < NT; ++nt) {
            constexpr int dummy = 0; (void)dummy;
            int h = (nt * 16) / D;
            pl[h] = fmaf(acc[nt][r], alv[nt], pl[h]);
            pr[h] = fmaf(acc[nt][r], arv[nt], pr[h]);
        }
        #pragma unroll
        for (int off = 1; off < 16; off <<= 1) {
            #pragma unroll
            for (int h = 0; h < H; ++h) {
                pl[h] += __shfl_xor(pl[h], off, 64);
                pr[h] += __shfl_xor(pr[h], off, 64);
            }
        }
        if (row < n) {
            #pragma unroll
            for (int nt = 0; nt < NT; ++nt)
                ftb[(size_t)row * (NT * 16) + nt * 16 + m] = f2bf(acc[nt][r]);
            if (m < H) {
                float vl = pl[0], vr = pr[0];
                #pragma unroll
                for (int h = 1; h < H; ++h)
                    if (m == h) { vl = pl[h]; vr = pr[h]; }
                el[row * H + m] = vl;
                er[row * H + m] = vr;
            }
        }
    }
}

// ---------------- fused GAT aggregate + ELU + LayerNorm + residual ----------------
// One wave per dst node; 128 dims as 2 bf16 (one uint)/lane; head = lane/16.
// Edge loop batched x4 (+unroll 2): up to 8 ftb-row gathers in flight.

__global__ __launch_bounds__(256) void gat_agg_ln(
    const int* __restrict__ rowptr, const int2* __restrict__ edge_s,
    const unsigned int* __restrict__ ftb2, const float* __restrict__ el,
    const float* __restrict__ er, const float* __restrict__ lam_p,
    const float* __restrict__ g, const float* __restrict__ b,
    const float* __restrict__ prev, float* __restrict__ out, int n) {
    int wid = blockIdx.x * 4 + (threadIdx.x >> 6);
    if (wid >= n) return;
    int lane = threadIdx.x & 63;
    int head = lane >> 4;
    float lam = lam_p[0];
    float erv = er[wid * 4 + head];
    int s0 = rowptr[wid], s1 = rowptr[wid + 1];
    float ax = 0.f, ay = 0.f, s = 0.f;

    int i = s0;
    #pragma unroll 2
    for (; i + 4 <= s1; i += 4) {
        int2 e0 = edge_s[i], e1 = edge_s[i + 1], e2 = edge_s[i + 2], e3 = edge_s[i + 3];
        unsigned u0 = ftb2[(size_t)e0.x * 64 + lane];
        unsigned u1 = ftb2[(size_t)e1.x * 64 + lane];
        unsigned u2 = ftb2[(size_t)e2.x * 64 + lane];
        unsigned u3 = ftb2[(size_t)e3.x * 64 + lane];
        float l0 = el[e0.x * 4 + head];
        float l1 = el[e1.x * 4 + head];
        float l2 = el[e2.x * 4 + head];
        float l3 = el[e3.x * 4 + head];
        float v0 = l0 + erv + lam * __int_as_float(e0.y);
        float v1 = l1 + erv + lam * __int_as_float(e1.y);
        float v2 = l2 + erv + lam * __int_as_float(e2.y);
        float v3 = l3 + erv + lam * __int_as_float(e3.y);
        v0 = (v0 >= 0.f) ? v0 : NEG_SLOPE * v0;
        v1 = (v1 >= 0.f) ? v1 : NEG_SLOPE * v1;
        v2 = (v2 >= 0.f) ? v2 : NEG_SLOPE * v2;
        v3 = (v3 >= 0.f) ? v3 : NEG_SLOPE * v3;
        float p0 = __expf(v0), p1 = __expf(v1), p2 = __expf(v2), p3 = __expf(v3);
        ax = fmaf(p0, __uint_as_float(u0 << 16), ax);
        ay = fmaf(p0, __uint_as_float(u0 & 0xFFFF0000u), ay);
        ax = fmaf(p1, __uint_as_float(u1 << 16), ax);
        ay = fmaf(p1, __uint_as_float(u1 & 0xFFFF0000u), ay);
        ax = fmaf(p2, __uint_as_float(u2 << 16), ax);
        ay = fmaf(p2, __uint_as_float(u2 & 0xFFFF0000u), ay);
        ax = fmaf(p3, __uint_as_float(u3 << 16), ax);
        ay = fmaf(p3, __uint_as_float(u3 & 0xFFFF0000u), ay);
        s += (p0 + p1) + (p2 + p3);
    }
    for (; i < s1; ++i) {
        int2 e = edge_s[i];
        unsigned u = ftb2[(size_t)e.x * 64 + lane];
        float v = el[e.x * 4 + head] + erv + lam * __int_as_float(e.y);
        v = (v >= 0.f) ? v : NEG_SLOPE * v;
        float p = __expf(v);
        ax = fmaf(p, __uint_as_float(u << 16), ax);
        ay = fmaf(p, __uint_as_float(u & 0xFFFF0000u), ay);
        s += p;
    }

    float inv = (s > 0.f) ? 1.f / s : 0.f;
    float x0 = ax * inv, x1 = ay * inv;
    x0 = (x0 > 0.f) ? x0 : expm1f(x0);
    x1 = (x1 > 0.f) ? x1 : expm1f(x1);
    float sum = x0 + x1, sq = x0 * x0 + x1 * x1;
    #pragma unroll
    for (int off = 32; off > 0; off >>= 1) {
        sum += __shfl_xor(sum, off, 64);
        sq += __shfl_xor(sq, off, 64);
    }
    float mu = sum * (1.f / 128.f);
    float var = sq * (1.f / 128.f) - mu * mu;
    float rs = rsqrtf(var + LN_EPS);
    float2 gv = ((const float2*)g)[lane];
    float2 bv = ((const float2*)b)[lane];
    float2 pv = ((const float2*)prev)[(size_t)wid * 64 + lane];
    float2 y;
    y.x = (x0 - mu) * rs * gv.x + bv.x + pv.x;
    y.y = (x1 - mu) * rs * gv.y + bv.y + pv.y;
    ((float2*)out)[(size_t)wid * 64 + lane] = y;
}

// Layer 2: H=1, OUT=64 (1 bf16/lane), no epilogue; writes both tuple halves.
__global__ __launch_bounds__(256) void gat_agg_out(
    const int* __restrict__ rowptr, const int2* __restrict__ edge_s,
    const unsigned short* __restrict__ ftb, const float* __restrict__ el,
    const float* __restrict__ er, const float* __restrict__ lam_p,
    float* __restrict__ out, int n) {
    int wid = blockIdx.x * 4 + (threadIdx.x >> 6);
    if (wid >= n) return;
    int lane = threadIdx.x & 63;
    float lam = lam_p[0];
    float erv = er[wid];
    int s0 = rowptr[wid], s1 = rowptr[wid + 1];
    float acc = 0.f, s = 0.f;

    int i = s0;
    #pragma unroll 2
    for (; i + 4 <= s1; i += 4) {
        int2 e0 = edge_s[i], e1 = edge_s[i + 1], e2 = edge_s[i + 2], e3 = edge_s[i + 3];
        unsigned f0 = ftb[(size_t)e0.x * 64 + lane];
        unsigned f1 = ftb[(size_t)e1.x * 64 + lane];
        unsigned f2 = ftb[(size_t)e2.x * 64 + lane];
        unsigned f3 = ftb[(size_t)e3.x * 64 + lane];
        float l0 = el[e0.x], l1 = el[e1.x], l2 = el[e2.x], l3 = el[e3.x];
        float v0 = l0 + erv + lam * __int_as_float(e0.y);
        float v1 = l1 + erv + lam * __int_as_float(e1.y);
        float v2 = l2 + erv + lam * __int_as_float(e2.y);
        float v3 = l3 + erv + lam * __int_as_float(e3.y);
        v0 = (v0 >= 0.f) ? v0 : NEG_SLOPE * v0;
        v1 = (v1 >= 0.f) ? v1 : NEG_SLOPE * v1;
        v2 = (v2 >= 0.f) ? v2 : NEG_SLOPE * v2;
        v3 = (v3 >= 0.f) ? v3 : NEG_SLOPE * v3;
        float p0 = __expf(v0), p1 = __expf(v1), p2 = __expf(v2), p3 = __expf(v3);
        acc = fmaf(p0, __uint_as_float(f0 << 16), acc);
        acc = fmaf(p1, __uint_as_float(f1 << 16), acc);
        acc = fmaf(p2, __uint_as_float(f2 << 16), acc);
        acc = fmaf(p3, __uint_as_float(f3 << 16), acc);
        s += (p0 + p1) + (p2 + p3);
    }
    for (; i < s1; ++i) {
        int2 e = edge_s[i];
        unsigned f = ftb[(size_t)e.x * 64 + lane];
        float v = el[e.x] + erv + lam * __int_as_float(e.y);
        v = (v >= 0.f) ? v : NEG_SLOPE * v;
        float p = __expf(v);
        acc = fmaf(p, __uint_as_float(f << 16), acc);
        s += p;
    }

    float inv = (s > 0.f) ? 1.f / s : 0.f;
    float v = acc * inv;
    out[(size_t)wid * 64 + lane] = v;
    out[(size_t)n * 64 + (size_t)wid * 64 + lane] = v;
}

// ---------------- launch ----------------

extern "C" void kernel_launch(void* const* d_in, const int* in_sizes, int n_in,
                              void* d_out, int out_size, void* d_ws, size_t ws_size,
                              hipStream_t stream) {
    const float* features = (const float*)d_in[0];
    const float* edge_weight = (const float*)d_in[1];
    const int* src = (const int*)d_in[2];
    const int* dst = (const int*)d_in[3];
    const float* W0 = (const float*)d_in[4];
    const float* al0 = (const float*)d_in[5];
    const float* ar0 = (const float*)d_in[6];
    const float* lam0 = (const float*)d_in[7];
    const float* W1 = (const float*)d_in[8];
    const float* al1 = (const float*)d_in[9];
    const float* ar1 = (const float*)d_in[10];
    const float* lam1 = (const float*)d_in[11];
    const float* W2 = (const float*)d_in[12];
    const float* al2 = (const float*)d_in[13];
    const float* ar2 = (const float*)d_in[14];
    const float* lam2 = (const float*)d_in[15];
    const float* g0 = (const float*)d_in[16];
    const float* b0 = (const float*)d_in[17];
    const float* g1 = (const float*)d_in[18];
    const float* b1 = (const float*)d_in[19];

    const int N = in_sizes[0] / 128;
    const int E = in_sizes[1];

    char* w = (char*)d_ws;
    size_t o = 0;
    auto carve = [&](size_t bytes) {
        char* p = w + o;
        o += (bytes + 255) & ~(size_t)255;
        return p;
    };
    int* counts = (int*)carve((size_t)N * 4);        // doubles as scatter cursor
    int* rowptr = (int*)carve((size_t)(N + 1) * 4);
    int* bsum = (int*)carve(256 * 4);
    int2* edge_s = (int2*)carve((size_t)E * 8);
    unsigned short* ftb = (unsigned short*)carve((size_t)N * 128 * 2);
    float* el = (float*)carve((size_t)N * 4 * 4);
    float* er = (float*)carve((size_t)N * 4 * 4);
    float* h1 = (float*)carve((size_t)N * 128 * 4);
    float* h2 = (float*)carve((size_t)N * 128 * 4);
    unsigned short* Wt0 = (unsigned short*)carve(128 * 128 * 2);
    unsigned short* Wt1 = (unsigned short*)carve(128 * 128 * 2);
    unsigned short* Wt2 = (unsigned short*)carve(64 * 128 * 2);

    const int nscan = (N + 255) / 256;
    const int ngemm = (N + 63) / 64;

    // CSR by dst (shared across the 3 layers)
    hipMemsetAsync(counts, 0, (size_t)N * 4, stream);
    hist_kernel<<<(E + 255) / 256, 256, 0, stream>>>(dst, counts, E);
    scan1_kernel<<<nscan, 256, 0, stream>>>(counts, bsum, N);
    scan2_kernel<<<1, 256, 0, stream>>>(bsum, nscan);
    scan3_kernel<<<(N + 1 + 255) / 256, 256, 0, stream>>>(counts, bsum, rowptr, N, E);
    scatter_kernel<<<(E + 255) / 256, 256, 0, stream>>>(src, dst, edge_weight, counts,
                                                        edge_s, E);
    // W transposes (tiny)
    wcast_kernel<<<128, 128, 0, stream>>>(W0, Wt0, 128);
    wcast_kernel<<<128, 128, 0, stream>>>(W1, Wt1, 128);
    wcast_kernel<<<64, 128, 0, stream>>>(W2, Wt2, 64);

    // Layer 0
    gemm_mfma<8, 4><<<ngemm, 256, 0, stream>>>(features, Wt0, al0, ar0, ftb, el, er, N);
    gat_agg_ln<<<(N + 3) / 4, 256, 0, stream>>>(rowptr, edge_s, (const unsigned int*)ftb,
                                                el, er, lam0, g0, b0, features, h1, N);
    // Layer 1
    gemm_mfma<8, 4><<<ngemm, 256, 0, stream>>>(h1, Wt1, al1, ar1, ftb, el, er, N);
    gat_agg_ln<<<(N + 3) / 4, 256, 0, stream>>>(rowptr, edge_s, (const unsigned int*)ftb,
                                                el, er, lam1, g1, b1, h1, h2, N);
    // Layer 2
    gemm_mfma<4, 1><<<ngemm, 256, 0, stream>>>(h2, Wt2, al2, ar2, ftb, el, er, N);
    gat_agg_out<<<(N + 3) / 4, 256, 0, stream>>>(rowptr, edge_s, ftb, el, er, lam2,
                                                 (float*)d_out, N);
}

// Round 7
// 342.848 us; speedup vs baseline: 3.2304x; 1.0585x over previous
//
#include <hip/hip_runtime.h>

#define NEG_SLOPE 0.2f
#define LN_EPS 1e-5f

typedef __attribute__((ext_vector_type(8))) short bf16x8;
typedef __attribute__((ext_vector_type(4))) float f32x4;

__device__ inline unsigned short f2bf(float f) {
    unsigned u = __float_as_uint(f);
    unsigned r = u + 0x7FFFu + ((u >> 16) & 1u);   // round-to-nearest-even
    return (unsigned short)(r >> 16);
}

// ---------------- CSR build ----------------

__global__ void hist_kernel(const int* __restrict__ dst, int* __restrict__ counts, int E) {
    int i = blockIdx.x * blockDim.x + threadIdx.x;
    if (i < E) atomicAdd(&counts[dst[i]], 1);
}

__global__ __launch_bounds__(256) void scan1_kernel(const int* __restrict__ counts,
                                                    int* __restrict__ bsum, int n) {
    __shared__ int lds[256];
    int t = threadIdx.x;
    int i = blockIdx.x * 256 + t;
    lds[t] = (i < n) ? counts[i] : 0;
    __syncthreads();
    for (int off = 128; off > 0; off >>= 1) {
        int v = (t < off) ? lds[t + off] : 0;
        __syncthreads();
        if (t < off) lds[t] += v;
        __syncthreads();
    }
    if (t == 0) bsum[blockIdx.x] = lds[0];
}

__global__ __launch_bounds__(256) void scan2_kernel(int* __restrict__ bsum, int nblocks) {
    __shared__ int lds[256];
    int t = threadIdx.x;
    int v0 = (t < nblocks) ? bsum[t] : 0;
    lds[t] = v0;
    __syncthreads();
    for (int off = 1; off < 256; off <<= 1) {
        int v = (t >= off) ? lds[t - off] : 0;
        __syncthreads();
        lds[t] += v;
        __syncthreads();
    }
    if (t < nblocks) bsum[t] = lds[t] - v0;  // exclusive
}

__global__ __launch_bounds__(256) void scan3_kernel(int* __restrict__ counts,
                                                    const int* __restrict__ bsum,
                                                    int* __restrict__ rowptr, int n, int E) {
    __shared__ int lds[256];
    int t = threadIdx.x;
    int i = blockIdx.x * 256 + t;
    int c = (i < n) ? counts[i] : 0;
    lds[t] = c;
    __syncthreads();
    for (int off = 1; off < 256; off <<= 1) {
        int v = (t >= off) ? lds[t - off] : 0;
        __syncthreads();
        lds[t] += v;
        __syncthreads();
    }
    int ex = bsum[blockIdx.x] + lds[t] - c;  // exclusive prefix
    if (i < n) {
        rowptr[i] = ex;
        counts[i] = ex;  // cursor for scatter
    }
    if (i == n) rowptr[n] = E;
}

// Packs (src, bitcast(ew)) into int2 so the agg loop does one 8B load per edge.
__global__ void scatter_kernel(const int* __restrict__ src, const int* __restrict__ dst,
                               const float* __restrict__ ew, int* __restrict__ cursor,
                               int2* __restrict__ edge_s, int E) {
    int i = blockIdx.x * blockDim.x + threadIdx.x;
    if (i < E) {
        int p = atomicAdd(&cursor[dst[i]], 1);
        edge_s[p] = make_int2(src[i], __float_as_int(ew[i]));
    }
}

// ---------------- W transpose-cast: Wt[n][k] bf16 <- W[k][n] fp32 ----------------

__global__ void wcast_kernel(const float* __restrict__ W, unsigned short* __restrict__ Wt,
                             int ncols) {
    int n = blockIdx.x;
    int k = threadIdx.x;
    Wt[n * 128 + k] = f2bf(W[k * ncols + n]);
}

// ---------------- MFMA GEMM + fused el/er + bf16 ft output ----------------

template <int NT, int H>
__global__ __launch_bounds__(256) void gemm_mfma(const float* __restrict__ A,
                                                 const unsigned short* __restrict__ Wt,
                                                 const float* __restrict__ al,
                                                 const float* __restrict__ ar,
                                                 unsigned short* __restrict__ ftb,
                                                 float* __restrict__ el,
                                                 float* __restrict__ er, int n) {
    constexpr int LDA = 136;  // bf16 elems per LDS row (128 + 8 pad)
    constexpr int D = NT * 16 / H;
    __shared__ unsigned short As[64 * LDA];
    __shared__ unsigned short Ws[NT * 16 * LDA];
    int t = threadIdx.x;
    int row0 = blockIdx.x * 64;

    const float4* A4 = (const float4*)A;
    #pragma unroll
    for (int j = 0; j < 8; ++j) {
        int idx = t + j * 256;
        int r = idx >> 5;
        int c4 = idx & 31;
        int row = row0 + r;
        float4 v = (row < n) ? A4[(size_t)row * 32 + c4] : make_float4(0.f, 0.f, 0.f, 0.f);
        unsigned p0 = (unsigned)f2bf(v.x) | ((unsigned)f2bf(v.y) << 16);
        unsigned p1 = (unsigned)f2bf(v.z) | ((unsigned)f2bf(v.w) << 16);
        *(uint2*)&As[r * LDA + c4 * 4] = make_uint2(p0, p1);
    }
    const uint4* Wg = (const uint4*)Wt;
    #pragma unroll
    for (int j = 0; j < NT; ++j) {
        int idx = t + j * 256;
        int r = idx >> 4;
        int c8 = idx & 15;
        *(uint4*)&Ws[r * LDA + c8 * 8] = Wg[idx];
    }
    __syncthreads();

    int w = t >> 6, lane = t & 63;
    int m = lane & 15, q = lane >> 4;
    f32x4 acc[NT] = {};
    const unsigned short* ap = &As[(w * 16 + m) * LDA + q * 8];
    #pragma unroll
    for (int kk = 0; kk < 4; ++kk) {
        bf16x8 a = *(const bf16x8*)(ap + kk * 32);
        #pragma unroll
        for (int nt = 0; nt < NT; ++nt) {
            bf16x8 b = *(const bf16x8*)&Ws[(nt * 16 + m) * LDA + kk * 32 + q * 8];
            acc[nt] = __builtin_amdgcn_mfma_f32_16x16x32_bf16(a, b, acc[nt], 0, 0, 0);
        }
    }

    float alv[NT], arv[NT];
    #pragma unroll
    for (int nt = 0; nt < NT; ++nt) {
        alv[nt] = al[nt * 16 + m];
        arv[nt] = ar[nt * 16 + m];
    }

    int orow = row0 + w * 16 + q * 4;
    #pragma unroll
    for (int r = 0; r < 4; ++r) {
        int row = orow + r;
        float pl[H] = {}, pr[H] = {};
        #pragma unroll
        for (int nt = 0; nt < NT; ++nt) {
            int h = (nt * 16) / D;
            pl[h] = fmaf(acc[nt][r], alv[nt], pl[h]);
            pr[h] = fmaf(acc[nt][r], arv[nt], pr[h]);
        }
        #pragma unroll
        for (int off = 1; off < 16; off <<= 1) {
            #pragma unroll
            for (int h = 0; h < H; ++h) {
                pl[h] += __shfl_xor(pl[h], off, 64);
                pr[h] += __shfl_xor(pr[h], off, 64);
            }
        }
        if (row < n) {
            #pragma unroll
            for (int nt = 0; nt < NT; ++nt)
                ftb[(size_t)row * (NT * 16) + nt * 16 + m] = f2bf(acc[nt][r]);
            if (m < H) {
                float vl = pl[0], vr = pr[0];
                #pragma unroll
                for (int h = 1; h < H; ++h)
                    if (m == h) { vl = pl[h]; vr = pr[h]; }
                el[row * H + m] = vl;
                er[row * H + m] = vr;
            }
        }
    }
}

// ---------------- fused GAT aggregate + ELU + LayerNorm + residual ----------------
// 4 nodes/wave, 16 lanes/node, 8 dims/lane (uint4 = 16B gather). One loop
// iteration advances one edge for each of 4 nodes -> per-edge overhead
// (edge record, el gather, logit, exp) amortized 4x vs the 1-node/wave form
// (R6 profile: VALUBusy 76%, overhead ~3x dim-work). Head = li>>2 (D=32).

__device__ inline void accum8(float* ax, uint4 u, float p) {
    ax[0] = fmaf(p, __uint_as_float(u.x << 16), ax[0]);
    ax[1] = fmaf(p, __uint_as_float(u.x & 0xFFFF0000u), ax[1]);
    ax[2] = fmaf(p, __uint_as_float(u.y << 16), ax[2]);
    ax[3] = fmaf(p, __uint_as_float(u.y & 0xFFFF0000u), ax[3]);
    ax[4] = fmaf(p, __uint_as_float(u.z << 16), ax[4]);
    ax[5] = fmaf(p, __uint_as_float(u.z & 0xFFFF0000u), ax[5]);
    ax[6] = fmaf(p, __uint_as_float(u.w << 16), ax[6]);
    ax[7] = fmaf(p, __uint_as_float(u.w & 0xFFFF0000u), ax[7]);
}

__global__ __launch_bounds__(256) void gat_agg_ln(
    const int* __restrict__ rowptr, const int2* __restrict__ edge_s,
    const uint4* __restrict__ ftb4, const float* __restrict__ el,
    const float* __restrict__ er, const float* __restrict__ lam_p,
    const float* __restrict__ g, const float* __restrict__ b,
    const float* __restrict__ prev, float* __restrict__ out, int n) {
    int node = blockIdx.x * 16 + (threadIdx.x >> 4);
    if (node >= n) return;
    int li = threadIdx.x & 15;
    int head = li >> 2;
    float lam = lam_p[0];
    float erv = er[node * 4 + head];
    int s0 = rowptr[node], s1 = rowptr[node + 1];
    float ax[8] = {};
    float s = 0.f;

    int i = s0;
    for (; i + 2 <= s1; i += 2) {
        int2 e0 = edge_s[i], e1 = edge_s[i + 1];
        uint4 u0 = ftb4[(size_t)e0.x * 16 + li];
        uint4 u1 = ftb4[(size_t)e1.x * 16 + li];
        float l0 = el[e0.x * 4 + head];
        float l1 = el[e1.x * 4 + head];
        float v0 = l0 + erv + lam * __int_as_float(e0.y);
        float v1 = l1 + erv + lam * __int_as_float(e1.y);
        v0 = fmaxf(v0, NEG_SLOPE * v0);
        v1 = fmaxf(v1, NEG_SLOPE * v1);
        float p0 = __expf(v0), p1 = __expf(v1);
        accum8(ax, u0, p0);
        accum8(ax, u1, p1);
        s += p0 + p1;
    }
    if (i < s1) {
        int2 e = edge_s[i];
        uint4 u = ftb4[(size_t)e.x * 16 + li];
        float v = el[e.x * 4 + head] + erv + lam * __int_as_float(e.y);
        v = fmaxf(v, NEG_SLOPE * v);
        float p = __expf(v);
        accum8(ax, u, p);
        s += p;
    }

    float inv = (s > 0.f) ? 1.f / s : 0.f;
    float x[8];
    float sum = 0.f, sq = 0.f;
    #pragma unroll
    for (int d = 0; d < 8; ++d) {
        float v = ax[d] * inv;
        v = (v > 0.f) ? v : expm1f(v);
        x[d] = v;
        sum += v;
        sq += v * v;
    }
    #pragma unroll
    for (int off = 1; off < 16; off <<= 1) {
        sum += __shfl_xor(sum, off, 16);
        sq += __shfl_xor(sq, off, 16);
    }
    float mu = sum * (1.f / 128.f);
    float var = sq * (1.f / 128.f) - mu * mu;
    float rs = rsqrtf(var + LN_EPS);

    const float4* g4 = (const float4*)g;
    const float4* b4 = (const float4*)b;
    const float4* p4 = (const float4*)prev;
    float4* o4 = (float4*)out;
    size_t base = (size_t)node * 32 + li * 2;
    #pragma unroll
    for (int h = 0; h < 2; ++h) {
        float4 gv = g4[li * 2 + h];
        float4 bv = b4[li * 2 + h];
        float4 pv = p4[base + h];
        float4 y;
        y.x = (x[h * 4 + 0] - mu) * rs * gv.x + bv.x + pv.x;
        y.y = (x[h * 4 + 1] - mu) * rs * gv.y + bv.y + pv.y;
        y.z = (x[h * 4 + 2] - mu) * rs * gv.z + bv.z + pv.z;
        y.w = (x[h * 4 + 3] - mu) * rs * gv.w + bv.w + pv.w;
        o4[base + h] = y;
    }
}

// Layer 2: H=1, OUT=64; 4 nodes/wave, 16 lanes/node, 4 dims/lane (uint2).
__global__ __launch_bounds__(256) void gat_agg_out(
    const int* __restrict__ rowptr, const int2* __restrict__ edge_s,
    const uint2* __restrict__ ftb2, const float* __restrict__ el,
    const float* __restrict__ er, const float* __restrict__ lam_p,
    float* __restrict__ out, int n) {
    int node = blockIdx.x * 16 + (threadIdx.x >> 4);
    if (node >= n) return;
    int li = threadIdx.x & 15;
    float lam = lam_p[0];
    float erv = er[node];
    int s0 = rowptr[node], s1 = rowptr[node + 1];
    float ax[4] = {};
    float s = 0.f;

    int i = s0;
    for (; i + 2 <= s1; i += 2) {
        int2 e0 = edge_s[i], e1 = edge_s[i + 1];
        uint2 u0 = ftb2[(size_t)e0.x * 16 + li];
        uint2 u1 = ftb2[(size_t)e1.x * 16 + li];
        float l0 = el[e0.x], l1 = el[e1.x];
        float v0 = l0 + erv + lam * __int_as_float(e0.y);
        float v1 = l1 + erv + lam * __int_as_float(e1.y);
        v0 = fmaxf(v0, NEG_SLOPE * v0);
        v1 = fmaxf(v1, NEG_SLOPE * v1);
        float p0 = __expf(v0), p1 = __expf(v1);
        ax[0] = fmaf(p0, __uint_as_float(u0.x << 16), ax[0]);
        ax[1] = fmaf(p0, __uint_as_float(u0.x & 0xFFFF0000u), ax[1]);
        ax[2] = fmaf(p0, __uint_as_float(u0.y << 16), ax[2]);
        ax[3] = fmaf(p0, __uint_as_float(u0.y & 0xFFFF0000u), ax[3]);
        ax[0] = fmaf(p1, __uint_as_float(u1.x << 16), ax[0]);
        ax[1] = fmaf(p1, __uint_as_float(u1.x & 0xFFFF0000u), ax[1]);
        ax[2] = fmaf(p1, __uint_as_float(u1.y << 16), ax[2]);
        ax[3] = fmaf(p1, __uint_as_float(u1.y & 0xFFFF0000u), ax[3]);
        s += p0 + p1;
    }
    if (i < s1) {
        int2 e = edge_s[i];
        uint2 u = ftb2[(size_t)e.x * 16 + li];
        float v = el[e.x] + erv + lam * __int_as_float(e.y);
        v = fmaxf(v, NEG_SLOPE * v);
        float p = __expf(v);
        ax[0] = fmaf(p, __uint_as_float(u.x << 16), ax[0]);
        ax[1] = fmaf(p, __uint_as_float(u.x & 0xFFFF0000u), ax[1]);
        ax[2] = fmaf(p, __uint_as_float(u.y << 16), ax[2]);
        ax[3] = fmaf(p, __uint_as_float(u.y & 0xFFFF0000u), ax[3]);
        s += p;
    }

    float inv = (s > 0.f) ? 1.f / s : 0.f;
    float4 y;
    y.x = ax[0] * inv;
    y.y = ax[1] * inv;
    y.z = ax[2] * inv;
    y.w = ax[3] * inv;
    ((float4*)out)[(size_t)node * 16 + li] = y;
    ((float4*)out)[(size_t)(n + node) * 16 + li] = y;
}

// ---------------- launch ----------------

extern "C" void kernel_launch(void* const* d_in, const int* in_sizes, int n_in,
                              void* d_out, int out_size, void* d_ws, size_t ws_size,
                              hipStream_t stream) {
    const float* features = (const float*)d_in[0];
    const float* edge_weight = (const float*)d_in[1];
    const int* src = (const int*)d_in[2];
    const int* dst = (const int*)d_in[3];
    const float* W0 = (const float*)d_in[4];
    const float* al0 = (const float*)d_in[5];
    const float* ar0 = (const float*)d_in[6];
    const float* lam0 = (const float*)d_in[7];
    const float* W1 = (const float*)d_in[8];
    const float* al1 = (const float*)d_in[9];
    const float* ar1 = (const float*)d_in[10];
    const float* lam1 = (const float*)d_in[11];
    const float* W2 = (const float*)d_in[12];
    const float* al2 = (const float*)d_in[13];
    const float* ar2 = (const float*)d_in[14];
    const float* lam2 = (const float*)d_in[15];
    const float* g0 = (const float*)d_in[16];
    const float* b0 = (const float*)d_in[17];
    const float* g1 = (const float*)d_in[18];
    const float* b1 = (const float*)d_in[19];

    const int N = in_sizes[0] / 128;
    const int E = in_sizes[1];

    char* w = (char*)d_ws;
    size_t o = 0;
    auto carve = [&](size_t bytes) {
        char* p = w + o;
        o += (bytes + 255) & ~(size_t)255;
        return p;
    };
    int* counts = (int*)carve((size_t)N * 4);        // doubles as scatter cursor
    int* rowptr = (int*)carve((size_t)(N + 1) * 4);
    int* bsum = (int*)carve(256 * 4);
    int2* edge_s = (int2*)carve((size_t)E * 8);
    unsigned short* ftb = (unsigned short*)carve((size_t)N * 128 * 2);
    float* el = (float*)carve((size_t)N * 4 * 4);
    float* er = (float*)carve((size_t)N * 4 * 4);
    float* h1 = (float*)carve((size_t)N * 128 * 4);
    float* h2 = (float*)carve((size_t)N * 128 * 4);
    unsigned short* Wt0 = (unsigned short*)carve(128 * 128 * 2);
    unsigned short* Wt1 = (unsigned short*)carve(128 * 128 * 2);
    unsigned short* Wt2 = (unsigned short*)carve(64 * 128 * 2);

    const int nscan = (N + 255) / 256;
    const int ngemm = (N + 63) / 64;
    const int nagg = (N + 15) / 16;

    // CSR by dst (shared across the 3 layers)
    hipMemsetAsync(counts, 0, (size_t)N * 4, stream);
    hist_kernel<<<(E + 255) / 256, 256, 0, stream>>>(dst, counts, E);
    scan1_kernel<<<nscan, 256, 0, stream>>>(counts, bsum, N);
    scan2_kernel<<<1, 256, 0, stream>>>(bsum, nscan);
    scan3_kernel<<<(N + 1 + 255) / 256, 256, 0, stream>>>(counts, bsum, rowptr, N, E);
    scatter_kernel<<<(E + 255) / 256, 256, 0, stream>>>(src, dst, edge_weight, counts,
                                                        edge_s, E);
    // W transposes (tiny)
    wcast_kernel<<<128, 128, 0, stream>>>(W0, Wt0, 128);
    wcast_kernel<<<128, 128, 0, stream>>>(W1, Wt1, 128);
    wcast_kernel<<<64, 128, 0, stream>>>(W2, Wt2, 64);

    // Layer 0
    gemm_mfma<8, 4><<<ngemm, 256, 0, stream>>>(features, Wt0, al0, ar0, ftb, el, er, N);
    gat_agg_ln<<<nagg, 256, 0, stream>>>(rowptr, edge_s, (const uint4*)ftb,
                                         el, er, lam0, g0, b0, features, h1, N);
    // Layer 1
    gemm_mfma<8, 4><<<ngemm, 256, 0, stream>>>(h1, Wt1, al1, ar1, ftb, el, er, N);
    gat_agg_ln<<<nagg, 256, 0, stream>>>(rowptr, edge_s, (const uint4*)ftb,
                                         el, er, lam1, g1, b1, h1, h2, N);
    // Layer 2
    gemm_mfma<4, 1><<<ngemm, 256, 0, stream>>>(h2, Wt2, al2, ar2, ftb, el, er, N);
    gat_agg_out<<<nagg, 256, 0, stream>>>(rowptr, edge_s, (const uint2*)ftb,
                                          el, er, lam2, (float*)d_out, N);
}

// Round 8
// 317.421 us; speedup vs baseline: 3.4892x; 1.0801x over previous
//
#include <hip/hip_runtime.h>

#define NEG_SLOPE 0.2f
#define LN_EPS 1e-5f

typedef __attribute__((ext_vector_type(8))) short bf16x8;
typedef __attribute__((ext_vector_type(4))) float f32x4;

__device__ inline unsigned short f2bf(float f) {
    unsigned u = __float_as_uint(f);
    unsigned r = u + 0x7FFFu + ((u >> 16) & 1u);   // round-to-nearest-even
    return (unsigned short)(r >> 16);
}

// ---------------- CSR build ----------------
// counts padded to one per 64B cacheline (idx*16) so cross-XCD atomic RMWs
// on a line serialize 16x less (R7: scatter was atomic-serialization bound,
// VALUBusy 0.4%). Single atomic pass: rank[i] = old count; place pass is
// atomic-free (rowptr gather + rank).

__global__ void rank_kernel(const int* __restrict__ dst, int* __restrict__ counts,
                            int* __restrict__ rank, int E) {
    int i = blockIdx.x * blockDim.x + threadIdx.x;
    if (i < E) rank[i] = atomicAdd(&counts[dst[i] * 16], 1);
}

__global__ __launch_bounds__(256) void scan1_kernel(const int* __restrict__ counts,
                                                    int* __restrict__ bsum, int n) {
    __shared__ int lds[256];
    int t = threadIdx.x;
    int i = blockIdx.x * 256 + t;
    lds[t] = (i < n) ? counts[i * 16] : 0;
    __syncthreads();
    for (int off = 128; off > 0; off >>= 1) {
        int v = (t < off) ? lds[t + off] : 0;
        __syncthreads();
        if (t < off) lds[t] += v;
        __syncthreads();
    }
    if (t == 0) bsum[blockIdx.x] = lds[0];
}

__global__ __launch_bounds__(256) void scan2_kernel(int* __restrict__ bsum, int nblocks) {
    __shared__ int lds[256];
    int t = threadIdx.x;
    int v0 = (t < nblocks) ? bsum[t] : 0;
    lds[t] = v0;
    __syncthreads();
    for (int off = 1; off < 256; off <<= 1) {
        int v = (t >= off) ? lds[t - off] : 0;
        __syncthreads();
        lds[t] += v;
        __syncthreads();
    }
    if (t < nblocks) bsum[t] = lds[t] - v0;  // exclusive
}

__global__ __launch_bounds__(256) void scan3_kernel(const int* __restrict__ counts,
                                                    const int* __restrict__ bsum,
                                                    int* __restrict__ rowptr, int n, int E) {
    __shared__ int lds[256];
    int t = threadIdx.x;
    int i = blockIdx.x * 256 + t;
    int c = (i < n) ? counts[i * 16] : 0;
    lds[t] = c;
    __syncthreads();
    for (int off = 1; off < 256; off <<= 1) {
        int v = (t >= off) ? lds[t - off] : 0;
        __syncthreads();
        lds[t] += v;
        __syncthreads();
    }
    if (i < n) rowptr[i] = bsum[blockIdx.x] + lds[t] - c;  // exclusive prefix
    if (i == n) rowptr[n] = E;
}

// Atomic-free placement; record packed to 4B: (bf16(ew)<<16) | src  (src<65536).
__global__ void place_kernel(const int* __restrict__ src, const int* __restrict__ dst,
                             const float* __restrict__ ew, const int* __restrict__ rowptr,
                             const int* __restrict__ rank, unsigned* __restrict__ edge_p,
                             int E) {
    int i = blockIdx.x * blockDim.x + threadIdx.x;
    if (i < E) {
        int p = rowptr[dst[i]] + rank[i];
        edge_p[p] = ((unsigned)f2bf(ew[i]) << 16) | (unsigned)src[i];
    }
}

// ---------------- W transpose-cast: Wt[n][k] bf16 <- W[k][n] fp32 ----------------

__global__ void wcast_kernel(const float* __restrict__ W, unsigned short* __restrict__ Wt,
                             int ncols) {
    int n = blockIdx.x;
    int k = threadIdx.x;
    Wt[n * 128 + k] = f2bf(W[k * ncols + n]);
}

// ---------------- MFMA GEMM + fused el/er + bf16 ft output ----------------

template <int NT, int H>
__global__ __launch_bounds__(256) void gemm_mfma(const float* __restrict__ A,
                                                 const unsigned short* __restrict__ Wt,
                                                 const float* __restrict__ al,
                                                 const float* __restrict__ ar,
                                                 unsigned short* __restrict__ ftb,
                                                 float* __restrict__ el,
                                                 float* __restrict__ er, int n) {
    constexpr int LDA = 136;  // bf16 elems per LDS row (128 + 8 pad)
    constexpr int D = NT * 16 / H;
    __shared__ unsigned short As[64 * LDA];
    __shared__ unsigned short Ws[NT * 16 * LDA];
    int t = threadIdx.x;
    int row0 = blockIdx.x * 64;

    const float4* A4 = (const float4*)A;
    #pragma unroll
    for (int j = 0; j < 8; ++j) {
        int idx = t + j * 256;
        int r = idx >> 5;
        int c4 = idx & 31;
        int row = row0 + r;
        float4 v = (row < n) ? A4[(size_t)row * 32 + c4] : make_float4(0.f, 0.f, 0.f, 0.f);
        unsigned p0 = (unsigned)f2bf(v.x) | ((unsigned)f2bf(v.y) << 16);
        unsigned p1 = (unsigned)f2bf(v.z) | ((unsigned)f2bf(v.w) << 16);
        *(uint2*)&As[r * LDA + c4 * 4] = make_uint2(p0, p1);
    }
    const uint4* Wg = (const uint4*)Wt;
    #pragma unroll
    for (int j = 0; j < NT; ++j) {
        int idx = t + j * 256;
        int r = idx >> 4;
        int c8 = idx & 15;
        *(uint4*)&Ws[r * LDA + c8 * 8] = Wg[idx];
    }
    __syncthreads();

    int w = t >> 6, lane = t & 63;
    int m = lane & 15, q = lane >> 4;
    f32x4 acc[NT] = {};
    const unsigned short* ap = &As[(w * 16 + m) * LDA + q * 8];
    #pragma unroll
    for (int kk = 0; kk < 4; ++kk) {
        bf16x8 a = *(const bf16x8*)(ap + kk * 32);
        #pragma unroll
        for (int nt = 0; nt < NT; ++nt) {
            bf16x8 b = *(const bf16x8*)&Ws[(nt * 16 + m) * LDA + kk * 32 + q * 8];
            acc[nt] = __builtin_amdgcn_mfma_f32_16x16x32_bf16(a, b, acc[nt], 0, 0, 0);
        }
    }

    float alv[NT], arv[NT];
    #pragma unroll
    for (int nt = 0; nt < NT; ++nt) {
        alv[nt] = al[nt * 16 + m];
        arv[nt] = ar[nt * 16 + m];
    }

    int orow = row0 + w * 16 + q * 4;
    #pragma unroll
    for (int r = 0; r < 4; ++r) {
        int row = orow + r;
        float pl[H] = {}, pr[H] = {};
        #pragma unroll
        for (int nt = 0; nt < NT; ++nt) {
            int h = (nt * 16) / D;
            pl[h] = fmaf(acc[nt][r], alv[nt], pl[h]);
            pr[h] = fmaf(acc[nt][r], arv[nt], pr[h]);
        }
        #pragma unroll
        for (int off = 1; off < 16; off <<= 1) {
            #pragma unroll
            for (int h = 0; h < H; ++h) {
                pl[h] += __shfl_xor(pl[h], off, 64);
                pr[h] += __shfl_xor(pr[h], off, 64);
            }
        }
        if (row < n) {
            #pragma unroll
            for (int nt = 0; nt < NT; ++nt)
                ftb[(size_t)row * (NT * 16) + nt * 16 + m] = f2bf(acc[nt][r]);
            if (m < H) {
                float vl = pl[0], vr = pr[0];
                #pragma unroll
                for (int h = 1; h < H; ++h)
                    if (m == h) { vl = pl[h]; vr = pr[h]; }
                el[row * H + m] = vl;
                er[row * H + m] = vr;
            }
        }
    }
}

// ---------------- fused GAT aggregate + ELU + LayerNorm + residual ----------------
// 4 nodes/wave, 16 lanes/node, 8 dims/lane (uint4 = 16B gather). Edge record
// is one packed uint: src = u & 0xFFFF, ew = bf16 in high half (unpack free).

__device__ inline void accum8(float* ax, uint4 u, float p) {
    ax[0] = fmaf(p, __uint_as_float(u.x << 16), ax[0]);
    ax[1] = fmaf(p, __uint_as_float(u.x & 0xFFFF0000u), ax[1]);
    ax[2] = fmaf(p, __uint_as_float(u.y << 16), ax[2]);
    ax[3] = fmaf(p, __uint_as_float(u.y & 0xFFFF0000u), ax[3]);
    ax[4] = fmaf(p, __uint_as_float(u.z << 16), ax[4]);
    ax[5] = fmaf(p, __uint_as_float(u.z & 0xFFFF0000u), ax[5]);
    ax[6] = fmaf(p, __uint_as_float(u.w << 16), ax[6]);
    ax[7] = fmaf(p, __uint_as_float(u.w & 0xFFFF0000u), ax[7]);
}

__global__ __launch_bounds__(256) void gat_agg_ln(
    const int* __restrict__ rowptr, const unsigned* __restrict__ edge_p,
    const uint4* __restrict__ ftb4, const float* __restrict__ el,
    const float* __restrict__ er, const float* __restrict__ lam_p,
    const float* __restrict__ g, const float* __restrict__ b,
    const float* __restrict__ prev, float* __restrict__ out, int n) {
    int node = blockIdx.x * 16 + (threadIdx.x >> 4);
    if (node >= n) return;
    int li = threadIdx.x & 15;
    int head = li >> 2;
    float lam = lam_p[0];
    float erv = er[node * 4 + head];
    int s0 = rowptr[node], s1 = rowptr[node + 1];
    float ax[8] = {};
    float s = 0.f;

    int i = s0;
    for (; i + 2 <= s1; i += 2) {
        unsigned e0 = edge_p[i], e1 = edge_p[i + 1];
        unsigned sn0 = e0 & 0xFFFFu, sn1 = e1 & 0xFFFFu;
        uint4 u0 = ftb4[(size_t)sn0 * 16 + li];
        uint4 u1 = ftb4[(size_t)sn1 * 16 + li];
        float l0 = el[sn0 * 4 + head];
        float l1 = el[sn1 * 4 + head];
        float v0 = l0 + erv + lam * __uint_as_float(e0 & 0xFFFF0000u);
        float v1 = l1 + erv + lam * __uint_as_float(e1 & 0xFFFF0000u);
        v0 = fmaxf(v0, NEG_SLOPE * v0);
        v1 = fmaxf(v1, NEG_SLOPE * v1);
        float p0 = __expf(v0), p1 = __expf(v1);
        accum8(ax, u0, p0);
        accum8(ax, u1, p1);
        s += p0 + p1;
    }
    if (i < s1) {
        unsigned e = edge_p[i];
        unsigned sn = e & 0xFFFFu;
        uint4 u = ftb4[(size_t)sn * 16 + li];
        float v = el[sn * 4 + head] + erv + lam * __uint_as_float(e & 0xFFFF0000u);
        v = fmaxf(v, NEG_SLOPE * v);
        float p = __expf(v);
        accum8(ax, u, p);
        s += p;
    }

    float inv = (s > 0.f) ? 1.f / s : 0.f;
    float x[8];
    float sum = 0.f, sq = 0.f;
    #pragma unroll
    for (int d = 0; d < 8; ++d) {
        float v = ax[d] * inv;
        v = (v > 0.f) ? v : expm1f(v);
        x[d] = v;
        sum += v;
        sq += v * v;
    }
    #pragma unroll
    for (int off = 1; off < 16; off <<= 1) {
        sum += __shfl_xor(sum, off, 16);
        sq += __shfl_xor(sq, off, 16);
    }
    float mu = sum * (1.f / 128.f);
    float var = sq * (1.f / 128.f) - mu * mu;
    float rs = rsqrtf(var + LN_EPS);

    const float4* g4 = (const float4*)g;
    const float4* b4 = (const float4*)b;
    const float4* p4 = (const float4*)prev;
    float4* o4 = (float4*)out;
    size_t base = (size_t)node * 32 + li * 2;
    #pragma unroll
    for (int h = 0; h < 2; ++h) {
        float4 gv = g4[li * 2 + h];
        float4 bv = b4[li * 2 + h];
        float4 pv = p4[base + h];
        float4 y;
        y.x = (x[h * 4 + 0] - mu) * rs * gv.x + bv.x + pv.x;
        y.y = (x[h * 4 + 1] - mu) * rs * gv.y + bv.y + pv.y;
        y.z = (x[h * 4 + 2] - mu) * rs * gv.z + bv.z + pv.z;
        y.w = (x[h * 4 + 3] - mu) * rs * gv.w + bv.w + pv.w;
        o4[base + h] = y;
    }
}

// Layer 2: H=1, OUT=64; 4 nodes/wave, 16 lanes/node, 4 dims/lane (uint2).
__global__ __launch_bounds__(256) void gat_agg_out(
    const int* __restrict__ rowptr, const unsigned* __restrict__ edge_p,
    const uint2* __restrict__ ftb2, const float* __restrict__ el,
    const float* __restrict__ er, const float* __restrict__ lam_p,
    float* __restrict__ out, int n) {
    int node = blockIdx.x * 16 + (threadIdx.x >> 4);
    if (node >= n) return;
    int li = threadIdx.x & 15;
    float lam = lam_p[0];
    float erv = er[node];
    int s0 = rowptr[node], s1 = rowptr[node + 1];
    float ax[4] = {};
    float s = 0.f;

    int i = s0;
    for (; i + 2 <= s1; i += 2) {
        unsigned e0 = edge_p[i], e1 = edge_p[i + 1];
        unsigned sn0 = e0 & 0xFFFFu, sn1 = e1 & 0xFFFFu;
        uint2 u0 = ftb2[(size_t)sn0 * 16 + li];
        uint2 u1 = ftb2[(size_t)sn1 * 16 + li];
        float l0 = el[sn0], l1 = el[sn1];
        float v0 = l0 + erv + lam * __uint_as_float(e0 & 0xFFFF0000u);
        float v1 = l1 + erv + lam * __uint_as_float(e1 & 0xFFFF0000u);
        v0 = fmaxf(v0, NEG_SLOPE * v0);
        v1 = fmaxf(v1, NEG_SLOPE * v1);
        float p0 = __expf(v0), p1 = __expf(v1);
        ax[0] = fmaf(p0, __uint_as_float(u0.x << 16), ax[0]);
        ax[1] = fmaf(p0, __uint_as_float(u0.x & 0xFFFF0000u), ax[1]);
        ax[2] = fmaf(p0, __uint_as_float(u0.y << 16), ax[2]);
        ax[3] = fmaf(p0, __uint_as_float(u0.y & 0xFFFF0000u), ax[3]);
        ax[0] = fmaf(p1, __uint_as_float(u1.x << 16), ax[0]);
        ax[1] = fmaf(p1, __uint_as_float(u1.x & 0xFFFF0000u), ax[1]);
        ax[2] = fmaf(p1, __uint_as_float(u1.y << 16), ax[2]);
        ax[3] = fmaf(p1, __uint_as_float(u1.y & 0xFFFF0000u), ax[3]);
        s += p0 + p1;
    }
    if (i < s1) {
        unsigned e = edge_p[i];
        unsigned sn = e & 0xFFFFu;
        uint2 u = ftb2[(size_t)sn * 16 + li];
        float v = el[sn] + erv + lam * __uint_as_float(e & 0xFFFF0000u);
        v = fmaxf(v, NEG_SLOPE * v);
        float p = __expf(v);
        ax[0] = fmaf(p, __uint_as_float(u.x << 16), ax[0]);
        ax[1] = fmaf(p, __uint_as_float(u.x & 0xFFFF0000u), ax[1]);
        ax[2] = fmaf(p, __uint_as_float(u.y << 16), ax[2]);
        ax[3] = fmaf(p, __uint_as_float(u.y & 0xFFFF0000u), ax[3]);
        s += p;
    }

    float inv = (s > 0.f) ? 1.f / s : 0.f;
    float4 y;
    y.x = ax[0] * inv;
    y.y = ax[1] * inv;
    y.z = ax[2] * inv;
    y.w = ax[3] * inv;
    ((float4*)out)[(size_t)node * 16 + li] = y;
    ((float4*)out)[(size_t)(n + node) * 16 + li] = y;
}

// ---------------- launch ----------------

extern "C" void kernel_launch(void* const* d_in, const int* in_sizes, int n_in,
                              void* d_out, int out_size, void* d_ws, size_t ws_size,
                              hipStream_t stream) {
    const float* features = (const float*)d_in[0];
    const float* edge_weight = (const float*)d_in[1];
    const int* src = (const int*)d_in[2];
    const int* dst = (const int*)d_in[3];
    const float* W0 = (const float*)d_in[4];
    const float* al0 = (const float*)d_in[5];
    const float* ar0 = (const float*)d_in[6];
    const float* lam0 = (const float*)d_in[7];
    const float* W1 = (const float*)d_in[8];
    const float* al1 = (const float*)d_in[9];
    const float* ar1 = (const float*)d_in[10];
    const float* lam1 = (const float*)d_in[11];
    const float* W2 = (const float*)d_in[12];
    const float* al2 = (const float*)d_in[13];
    const float* ar2 = (const float*)d_in[14];
    const float* lam2 = (const float*)d_in[15];
    const float* g0 = (const float*)d_in[16];
    const float* b0 = (const float*)d_in[17];
    const float* g1 = (const float*)d_in[18];
    const float* b1 = (const float*)d_in[19];

    const int N = in_sizes[0] / 128;   // 50000 (< 65536: src fits 16 bits)
    const int E = in_sizes[1];

    char* w = (char*)d_ws;
    size_t o = 0;
    auto carve = [&](size_t bytes) {
        char* p = w + o;
        o += (bytes + 255) & ~(size_t)255;
        return p;
    };
    int* counts = (int*)carve((size_t)N * 64);       // 1 counter per 64B line
    int* rowptr = (int*)carve((size_t)(N + 1) * 4);
    int* bsum = (int*)carve(256 * 4);
    int* rank = (int*)carve((size_t)E * 4);
    unsigned* edge_p = (unsigned*)carve((size_t)E * 4);
    unsigned short* ftb = (unsigned short*)carve((size_t)N * 128 * 2);
    float* el = (float*)carve((size_t)N * 4 * 4);
    float* er = (float*)carve((size_t)N * 4 * 4);
    float* h1 = (float*)carve((size_t)N * 128 * 4);
    float* h2 = (float*)carve((size_t)N * 128 * 4);
    unsigned short* Wt0 = (unsigned short*)carve(128 * 128 * 2);
    unsigned short* Wt1 = (unsigned short*)carve(128 * 128 * 2);
    unsigned short* Wt2 = (unsigned short*)carve(64 * 128 * 2);

    const int nscan = (N + 255) / 256;
    const int ngemm = (N + 63) / 64;
    const int nagg = (N + 15) / 16;

    // CSR by dst (shared across the 3 layers); single atomic pass
    hipMemsetAsync(counts, 0, (size_t)N * 64, stream);
    rank_kernel<<<(E + 255) / 256, 256, 0, stream>>>(dst, counts, rank, E);
    scan1_kernel<<<nscan, 256, 0, stream>>>(counts, bsum, N);
    scan2_kernel<<<1, 256, 0, stream>>>(bsum, nscan);
    scan3_kernel<<<(N + 1 + 255) / 256, 256, 0, stream>>>(counts, bsum, rowptr, N, E);
    place_kernel<<<(E + 255) / 256, 256, 0, stream>>>(src, dst, edge_weight, rowptr,
                                                      rank, edge_p, E);
    // W transposes (tiny)
    wcast_kernel<<<128, 128, 0, stream>>>(W0, Wt0, 128);
    wcast_kernel<<<128, 128, 0, stream>>>(W1, Wt1, 128);
    wcast_kernel<<<64, 128, 0, stream>>>(W2, Wt2, 64);

    // Layer 0
    gemm_mfma<8, 4><<<ngemm, 256, 0, stream>>>(features, Wt0, al0, ar0, ftb, el, er, N);
    gat_agg_ln<<<nagg, 256, 0, stream>>>(rowptr, edge_p, (const uint4*)ftb,
                                         el, er, lam0, g0, b0, features, h1, N);
    // Layer 1
    gemm_mfma<8, 4><<<ngemm, 256, 0, stream>>>(h1, Wt1, al1, ar1, ftb, el, er, N);
    gat_agg_ln<<<nagg, 256, 0, stream>>>(rowptr, edge_p, (const uint4*)ftb,
                                         el, er, lam1, g1, b1, h1, h2, N);
    // Layer 2
    gemm_mfma<4, 1><<<ngemm, 256, 0, stream>>>(h2, Wt2, al2, ar2, ftb, el, er, N);
    gat_agg_out<<<nagg, 256, 0, stream>>>(rowptr, edge_p, (const uint2*)ftb,
                                          el, er, lam2, (float*)d_out, N);
}

// Round 9
// 307.888 us; speedup vs baseline: 3.5972x; 1.0310x over previous
//
#include <hip/hip_runtime.h>

#define NEG_SLOPE 0.2f
#define LN_EPS 1e-5f

typedef __attribute__((ext_vector_type(8))) short bf16x8;
typedef __attribute__((ext_vector_type(4))) float f32x4;

__device__ inline unsigned short f2bf(float f) {
    unsigned u = __float_as_uint(f);
    unsigned r = u + 0x7FFFu + ((u >> 16) & 1u);   // round-to-nearest-even
    return (unsigned short)(r >> 16);
}

__device__ inline void unpack8(uint4 u, float* f) {
    f[0] = __uint_as_float(u.x << 16);
    f[1] = __uint_as_float(u.x & 0xFFFF0000u);
    f[2] = __uint_as_float(u.y << 16);
    f[3] = __uint_as_float(u.y & 0xFFFF0000u);
    f[4] = __uint_as_float(u.z << 16);
    f[5] = __uint_as_float(u.z & 0xFFFF0000u);
    f[6] = __uint_as_float(u.w << 16);
    f[7] = __uint_as_float(u.w & 0xFFFF0000u);
}

// ---------------- CSR build ----------------
// counts padded to one per 64B line (atomic serialization, R7). Single atomic
// pass produces rank; place is atomic-free. Edge record packed to 4B:
// (bf16(ew)<<16) | src  (src < 65536).

__global__ void rank_kernel(const int* __restrict__ dst, int* __restrict__ counts,
                            int* __restrict__ rank, int E) {
    int i = blockIdx.x * blockDim.x + threadIdx.x;
    if (i < E) rank[i] = atomicAdd(&counts[dst[i] * 16], 1);
}

__global__ __launch_bounds__(256) void scan1_kernel(const int* __restrict__ counts,
                                                    int* __restrict__ bsum, int n) {
    __shared__ int lds[256];
    int t = threadIdx.x;
    int i = blockIdx.x * 256 + t;
    lds[t] = (i < n) ? counts[i * 16] : 0;
    __syncthreads();
    for (int off = 128; off > 0; off >>= 1) {
        int v = (t < off) ? lds[t + off] : 0;
        __syncthreads();
        if (t < off) lds[t] += v;
        __syncthreads();
    }
    if (t == 0) bsum[blockIdx.x] = lds[0];
}

__global__ __launch_bounds__(256) void scan2_kernel(int* __restrict__ bsum, int nblocks) {
    __shared__ int lds[256];
    int t = threadIdx.x;
    int v0 = (t < nblocks) ? bsum[t] : 0;
    lds[t] = v0;
    __syncthreads();
    for (int off = 1; off < 256; off <<= 1) {
        int v = (t >= off) ? lds[t - off] : 0;
        __syncthreads();
        lds[t] += v;
        __syncthreads();
    }
    if (t < nblocks) bsum[t] = lds[t] - v0;  // exclusive
}

__global__ __launch_bounds__(256) void scan3_kernel(const int* __restrict__ counts,
                                                    const int* __restrict__ bsum,
                                                    int* __restrict__ rowptr, int n, int E) {
    __shared__ int lds[256];
    int t = threadIdx.x;
    int i = blockIdx.x * 256 + t;
    int c = (i < n) ? counts[i * 16] : 0;
    lds[t] = c;
    __syncthreads();
    for (int off = 1; off < 256; off <<= 1) {
        int v = (t >= off) ? lds[t - off] : 0;
        __syncthreads();
        lds[t] += v;
        __syncthreads();
    }
    if (i < n) rowptr[i] = bsum[blockIdx.x] + lds[t] - c;  // exclusive prefix
    if (i == n) rowptr[n] = E;
}

__global__ void place_kernel(const int* __restrict__ src, const int* __restrict__ dst,
                             const float* __restrict__ ew, const int* __restrict__ rowptr,
                             const int* __restrict__ rank, unsigned* __restrict__ edge_p,
                             int E) {
    int i = blockIdx.x * blockDim.x + threadIdx.x;
    if (i < E) {
        int p = rowptr[dst[i]] + rank[i];
        edge_p[p] = ((unsigned)f2bf(ew[i]) << 16) | (unsigned)src[i];
    }
}

// ---------------- casts ----------------

// features fp32 -> bf16 (packed), straight layout
__global__ void fcast_kernel(const float4* __restrict__ in, uint2* __restrict__ out, int n4) {
    int i = blockIdx.x * blockDim.x + threadIdx.x;
    if (i < n4) {
        float4 v = in[i];
        out[i] = make_uint2((unsigned)f2bf(v.x) | ((unsigned)f2bf(v.y) << 16),
                            (unsigned)f2bf(v.z) | ((unsigned)f2bf(v.w) << 16));
    }
}

// All three W transposes in one launch: Wt[n][k] bf16 <- W[k][n] fp32
__global__ void wcast_all(const float* __restrict__ W0, const float* __restrict__ W1,
                          const float* __restrict__ W2, unsigned short* __restrict__ Wt0,
                          unsigned short* __restrict__ Wt1, unsigned short* __restrict__ Wt2) {
    int bn = blockIdx.x, k = threadIdx.x;
    if (bn < 128) {
        Wt0[bn * 128 + k] = f2bf(W0[k * 128 + bn]);
    } else if (bn < 256) {
        int c = bn - 128;
        Wt1[c * 128 + k] = f2bf(W1[k * 128 + c]);
    } else {
        int c = bn - 256;
        Wt2[c * 128 + k] = f2bf(W2[k * 64 + c]);
    }
}

// ---------------- MFMA GEMM (bf16 A) + fused el/er + bf16 ft output ----------------
// A is bf16 [n][128] (16 uint4/row): staging is a pure copy now.

template <int NT, int H>
__global__ __launch_bounds__(256) void gemm_mfma(const uint4* __restrict__ A,
                                                 const unsigned short* __restrict__ Wt,
                                                 const float* __restrict__ al,
                                                 const float* __restrict__ ar,
                                                 unsigned short* __restrict__ ftb,
                                                 float* __restrict__ el,
                                                 float* __restrict__ er, int n) {
    constexpr int LDA = 136;  // bf16 elems per LDS row (128 + 8 pad)
    constexpr int D = NT * 16 / H;
    __shared__ unsigned short As[64 * LDA];
    __shared__ unsigned short Ws[NT * 16 * LDA];
    int t = threadIdx.x;
    int row0 = blockIdx.x * 64;

    #pragma unroll
    for (int j = 0; j < 4; ++j) {
        int idx = t + j * 256;  // uint4 index within 64x128 bf16 tile
        int r = idx >> 4;
        int c8 = idx & 15;
        int row = row0 + r;
        uint4 v = (row < n) ? A[(size_t)row * 16 + c8] : make_uint4(0, 0, 0, 0);
        *(uint4*)&As[r * LDA + c8 * 8] = v;
    }
    const uint4* Wg = (const uint4*)Wt;
    #pragma unroll
    for (int j = 0; j < NT; ++j) {
        int idx = t + j * 256;
        int r = idx >> 4;
        int c8 = idx & 15;
        *(uint4*)&Ws[r * LDA + c8 * 8] = Wg[idx];
    }
    __syncthreads();

    int w = t >> 6, lane = t & 63;
    int m = lane & 15, q = lane >> 4;
    f32x4 acc[NT] = {};
    const unsigned short* ap = &As[(w * 16 + m) * LDA + q * 8];
    #pragma unroll
    for (int kk = 0; kk < 4; ++kk) {
        bf16x8 a = *(const bf16x8*)(ap + kk * 32);
        #pragma unroll
        for (int nt = 0; nt < NT; ++nt) {
            bf16x8 b = *(const bf16x8*)&Ws[(nt * 16 + m) * LDA + kk * 32 + q * 8];
            acc[nt] = __builtin_amdgcn_mfma_f32_16x16x32_bf16(a, b, acc[nt], 0, 0, 0);
        }
    }

    float alv[NT], arv[NT];
    #pragma unroll
    for (int nt = 0; nt < NT; ++nt) {
        alv[nt] = al[nt * 16 + m];
        arv[nt] = ar[nt * 16 + m];
    }

    int orow = row0 + w * 16 + q * 4;
    #pragma unroll
    for (int r = 0; r < 4; ++r) {
        int row = orow + r;
        float pl[H] = {}, pr[H] = {};
        #pragma unroll
        for (int nt = 0; nt < NT; ++nt) {
            int h = (nt * 16) / D;
            pl[h] = fmaf(acc[nt][r], alv[nt], pl[h]);
            pr[h] = fmaf(acc[nt][r], arv[nt], pr[h]);
        }
        #pragma unroll
        for (int off = 1; off < 16; off <<= 1) {
            #pragma unroll
            for (int h = 0; h < H; ++h) {
                pl[h] += __shfl_xor(pl[h], off, 64);
                pr[h] += __shfl_xor(pr[h], off, 64);
            }
        }
        if (row < n) {
            #pragma unroll
            for (int nt = 0; nt < NT; ++nt)
                ftb[(size_t)row * (NT * 16) + nt * 16 + m] = f2bf(acc[nt][r]);
            if (m < H) {
                float vl = pl[0], vr = pr[0];
                #pragma unroll
                for (int h = 1; h < H; ++h)
                    if (m == h) { vl = pl[h]; vr = pr[h]; }
                el[row * H + m] = vl;
                er[row * H + m] = vr;
            }
        }
    }
}

// ---------------- fused GAT aggregate + ELU + LayerNorm + residual ----------------
// 4 nodes/wave, 16 lanes/node, 8 dims/lane. Edge loop batched x4 (R8: gather-
// latency-bound; 4 independent 16B gathers in flight). prev/out are bf16.

__device__ inline void accum8(float* ax, uint4 u, float p) {
    ax[0] = fmaf(p, __uint_as_float(u.x << 16), ax[0]);
    ax[1] = fmaf(p, __uint_as_float(u.x & 0xFFFF0000u), ax[1]);
    ax[2] = fmaf(p, __uint_as_float(u.y << 16), ax[2]);
    ax[3] = fmaf(p, __uint_as_float(u.y & 0xFFFF0000u), ax[3]);
    ax[4] = fmaf(p, __uint_as_float(u.z << 16), ax[4]);
    ax[5] = fmaf(p, __uint_as_float(u.z & 0xFFFF0000u), ax[5]);
    ax[6] = fmaf(p, __uint_as_float(u.w << 16), ax[6]);
    ax[7] = fmaf(p, __uint_as_float(u.w & 0xFFFF0000u), ax[7]);
}

__global__ __launch_bounds__(256) void gat_agg_ln(
    const int* __restrict__ rowptr, const unsigned* __restrict__ edge_p,
    const uint4* __restrict__ ftb4, const float* __restrict__ el,
    const float* __restrict__ er, const float* __restrict__ lam_p,
    const float* __restrict__ g, const float* __restrict__ b,
    const uint4* __restrict__ prevb, uint4* __restrict__ outb, int n) {
    int node = blockIdx.x * 16 + (threadIdx.x >> 4);
    if (node >= n) return;
    int li = threadIdx.x & 15;
    int head = li >> 2;
    float lam = lam_p[0];
    float erv = er[node * 4 + head];
    int s0 = rowptr[node], s1 = rowptr[node + 1];
    float ax[8] = {};
    float s = 0.f;

    int i = s0;
    for (; i + 4 <= s1; i += 4) {
        unsigned e0 = edge_p[i], e1 = edge_p[i + 1], e2 = edge_p[i + 2], e3 = edge_p[i + 3];
        unsigned sn0 = e0 & 0xFFFFu, sn1 = e1 & 0xFFFFu, sn2 = e2 & 0xFFFFu, sn3 = e3 & 0xFFFFu;
        uint4 u0 = ftb4[(size_t)sn0 * 16 + li];
        uint4 u1 = ftb4[(size_t)sn1 * 16 + li];
        uint4 u2 = ftb4[(size_t)sn2 * 16 + li];
        uint4 u3 = ftb4[(size_t)sn3 * 16 + li];
        float l0 = el[sn0 * 4 + head];
        float l1 = el[sn1 * 4 + head];
        float l2 = el[sn2 * 4 + head];
        float l3 = el[sn3 * 4 + head];
        float v0 = l0 + erv + lam * __uint_as_float(e0 & 0xFFFF0000u);
        float v1 = l1 + erv + lam * __uint_as_float(e1 & 0xFFFF0000u);
        float v2 = l2 + erv + lam * __uint_as_float(e2 & 0xFFFF0000u);
        float v3 = l3 + erv + lam * __uint_as_float(e3 & 0xFFFF0000u);
        v0 = fmaxf(v0, NEG_SLOPE * v0);
        v1 = fmaxf(v1, NEG_SLOPE * v1);
        v2 = fmaxf(v2, NEG_SLOPE * v2);
        v3 = fmaxf(v3, NEG_SLOPE * v3);
        float p0 = __expf(v0), p1 = __expf(v1), p2 = __expf(v2), p3 = __expf(v3);
        accum8(ax, u0, p0);
        accum8(ax, u1, p1);
        accum8(ax, u2, p2);
        accum8(ax, u3, p3);
        s += (p0 + p1) + (p2 + p3);
    }
    for (; i < s1; ++i) {
        unsigned e = edge_p[i];
        unsigned sn = e & 0xFFFFu;
        uint4 u = ftb4[(size_t)sn * 16 + li];
        float v = el[sn * 4 + head] + erv + lam * __uint_as_float(e & 0xFFFF0000u);
        v = fmaxf(v, NEG_SLOPE * v);
        float p = __expf(v);
        accum8(ax, u, p);
        s += p;
    }

    float inv = (s > 0.f) ? 1.f / s : 0.f;
    float x[8];
    float sum = 0.f, sq = 0.f;
    #pragma unroll
    for (int d = 0; d < 8; ++d) {
        float v = ax[d] * inv;
        v = (v > 0.f) ? v : expm1f(v);
        x[d] = v;
        sum += v;
        sq += v * v;
    }
    #pragma unroll
    for (int off = 1; off < 16; off <<= 1) {
        sum += __shfl_xor(sum, off, 16);
        sq += __shfl_xor(sq, off, 16);
    }
    float mu = sum * (1.f / 128.f);
    float var = sq * (1.f / 128.f) - mu * mu;
    float rs = rsqrtf(var + LN_EPS);

    const float4* g4 = (const float4*)g;
    const float4* b4 = (const float4*)b;
    float pv[8];
    unpack8(prevb[(size_t)node * 16 + li], pv);
    float y[8];
    #pragma unroll
    for (int h = 0; h < 2; ++h) {
        float4 gv = g4[li * 2 + h];
        float4 bv = b4[li * 2 + h];
        y[h * 4 + 0] = (x[h * 4 + 0] - mu) * rs * gv.x + bv.x + pv[h * 4 + 0];
        y[h * 4 + 1] = (x[h * 4 + 1] - mu) * rs * gv.y + bv.y + pv[h * 4 + 1];
        y[h * 4 + 2] = (x[h * 4 + 2] - mu) * rs * gv.z + bv.z + pv[h * 4 + 2];
        y[h * 4 + 3] = (x[h * 4 + 3] - mu) * rs * gv.w + bv.w + pv[h * 4 + 3];
    }
    uint4 o;
    o.x = (unsigned)f2bf(y[0]) | ((unsigned)f2bf(y[1]) << 16);
    o.y = (unsigned)f2bf(y[2]) | ((unsigned)f2bf(y[3]) << 16);
    o.z = (unsigned)f2bf(y[4]) | ((unsigned)f2bf(y[5]) << 16);
    o.w = (unsigned)f2bf(y[6]) | ((unsigned)f2bf(y[7]) << 16);
    outb[(size_t)node * 16 + li] = o;
}

// Layer 2: H=1, OUT=64; 4 nodes/wave, 16 lanes/node, 4 dims/lane (uint2), x4 batch.
__global__ __launch_bounds__(256) void gat_agg_out(
    const int* __restrict__ rowptr, const unsigned* __restrict__ edge_p,
    const uint2* __restrict__ ftb2, const float* __restrict__ el,
    const float* __restrict__ er, const float* __restrict__ lam_p,
    float* __restrict__ out, int n) {
    int node = blockIdx.x * 16 + (threadIdx.x >> 4);
    if (node >= n) return;
    int li = threadIdx.x & 15;
    float lam = lam_p[0];
    float erv = er[node];
    int s0 = rowptr[node], s1 = rowptr[node + 1];
    float ax[4] = {};
    float s = 0.f;

    int i = s0;
    for (; i + 4 <= s1; i += 4) {
        unsigned e0 = edge_p[i], e1 = edge_p[i + 1], e2 = edge_p[i + 2], e3 = edge_p[i + 3];
        unsigned sn0 = e0 & 0xFFFFu, sn1 = e1 & 0xFFFFu, sn2 = e2 & 0xFFFFu, sn3 = e3 & 0xFFFFu;
        uint2 u0 = ftb2[(size_t)sn0 * 16 + li];
        uint2 u1 = ftb2[(size_t)sn1 * 16 + li];
        uint2 u2 = ftb2[(size_t)sn2 * 16 + li];
        uint2 u3 = ftb2[(size_t)sn3 * 16 + li];
        float l0 = el[sn0], l1 = el[sn1], l2 = el[sn2], l3 = el[sn3];
        float v0 = l0 + erv + lam * __uint_as_float(e0 & 0xFFFF0000u);
        float v1 = l1 + erv + lam * __uint_as_float(e1 & 0xFFFF0000u);
        float v2 = l2 + erv + lam * __uint_as_float(e2 & 0xFFFF0000u);
        float v3 = l3 + erv + lam * __uint_as_float(e3 & 0xFFFF0000u);
        v0 = fmaxf(v0, NEG_SLOPE * v0);
        v1 = fmaxf(v1, NEG_SLOPE * v1);
        v2 = fmaxf(v2, NEG_SLOPE * v2);
        v3 = fmaxf(v3, NEG_SLOPE * v3);
        float p0 = __expf(v0), p1 = __expf(v1), p2 = __expf(v2), p3 = __expf(v3);
        ax[0] = fmaf(p0, __uint_as_float(u0.x << 16), ax[0]);
        ax[1] = fmaf(p0, __uint_as_float(u0.x & 0xFFFF0000u), ax[1]);
        ax[2] = fmaf(p0, __uint_as_float(u0.y << 16), ax[2]);
        ax[3] = fmaf(p0, __uint_as_float(u0.y & 0xFFFF0000u), ax[3]);
        ax[0] = fmaf(p1, __uint_as_float(u1.x << 16), ax[0]);
        ax[1] = fmaf(p1, __uint_as_float(u1.x & 0xFFFF0000u), ax[1]);
        ax[2] = fmaf(p1, __uint_as_float(u1.y << 16), ax[2]);
        ax[3] = fmaf(p1, __uint_as_float(u1.y & 0xFFFF0000u), ax[3]);
        ax[0] = fmaf(p2, __uint_as_float(u2.x << 16), ax[0]);
        ax[1] = fmaf(p2, __uint_as_float(u2.x & 0xFFFF0000u), ax[1]);
        ax[2] = fmaf(p2, __uint_as_float(u2.y << 16), ax[2]);
        ax[3] = fmaf(p2, __uint_as_float(u2.y & 0xFFFF0000u), ax[3]);
        ax[0] = fmaf(p3, __uint_as_float(u3.x << 16), ax[0]);
        ax[1] = fmaf(p3, __uint_as_float(u3.x & 0xFFFF0000u), ax[1]);
        ax[2] = fmaf(p3, __uint_as_float(u3.y << 16), ax[2]);
        ax[3] = fmaf(p3, __uint_as_float(u3.y & 0xFFFF0000u), ax[3]);
        s += (p0 + p1) + (p2 + p3);
    }
    for (; i < s1; ++i) {
        unsigned e = edge_p[i];
        unsigned sn = e & 0xFFFFu;
        uint2 u = ftb2[(size_t)sn * 16 + li];
        float v = el[sn] + erv + lam * __uint_as_float(e & 0xFFFF0000u);
        v = fmaxf(v, NEG_SLOPE * v);
        float p = __expf(v);
        ax[0] = fmaf(p, __uint_as_float(u.x << 16), ax[0]);
        ax[1] = fmaf(p, __uint_as_float(u.x & 0xFFFF0000u), ax[1]);
        ax[2] = fmaf(p, __uint_as_float(u.y << 16), ax[2]);
        ax[3] = fmaf(p, __uint_as_float(u.y & 0xFFFF0000u), ax[3]);
        s += p;
    }

    float inv = (s > 0.f) ? 1.f / s : 0.f;
    float4 y;
    y.x = ax[0] * inv;
    y.y = ax[1] * inv;
    y.z = ax[2] * inv;
    y.w = ax[3] * inv;
    ((float4*)out)[(size_t)node * 16 + li] = y;
    ((float4*)out)[(size_t)(n + node) * 16 + li] = y;
}

// ---------------- launch ----------------

extern "C" void kernel_launch(void* const* d_in, const int* in_sizes, int n_in,
                              void* d_out, int out_size, void* d_ws, size_t ws_size,
                              hipStream_t stream) {
    const float* features = (const float*)d_in[0];
    const float* edge_weight = (const float*)d_in[1];
    const int* src = (const int*)d_in[2];
    const int* dst = (const int*)d_in[3];
    const float* W0 = (const float*)d_in[4];
    const float* al0 = (const float*)d_in[5];
    const float* ar0 = (const float*)d_in[6];
    const float* lam0 = (const float*)d_in[7];
    const float* W1 = (const float*)d_in[8];
    const float* al1 = (const float*)d_in[9];
    const float* ar1 = (const float*)d_in[10];
    const float* lam1 = (const float*)d_in[11];
    const float* W2 = (const float*)d_in[12];
    const float* al2 = (const float*)d_in[13];
    const float* ar2 = (const float*)d_in[14];
    const float* lam2 = (const float*)d_in[15];
    const float* g0 = (const float*)d_in[16];
    const float* b0 = (const float*)d_in[17];
    const float* g1 = (const float*)d_in[18];
    const float* b1 = (const float*)d_in[19];

    const int N = in_sizes[0] / 128;   // 50000 (< 65536: src fits 16 bits)
    const int E = in_sizes[1];

    char* w = (char*)d_ws;
    size_t o = 0;
    auto carve = [&](size_t bytes) {
        char* p = w + o;
        o += (bytes + 255) & ~(size_t)255;
        return p;
    };
    int* counts = (int*)carve((size_t)N * 64);       // 1 counter per 64B line
    int* rowptr = (int*)carve((size_t)(N + 1) * 4);
    int* bsum = (int*)carve(256 * 4);
    int* rank = (int*)carve((size_t)E * 4);
    unsigned* edge_p = (unsigned*)carve((size_t)E * 4);
    unsigned short* ftb = (unsigned short*)carve((size_t)N * 128 * 2);
    unsigned short* f0b = (unsigned short*)carve((size_t)N * 128 * 2);
    unsigned short* h1 = (unsigned short*)carve((size_t)N * 128 * 2);
    unsigned short* h2 = (unsigned short*)carve((size_t)N * 128 * 2);
    float* el = (float*)carve((size_t)N * 4 * 4);
    float* er = (float*)carve((size_t)N * 4 * 4);
    unsigned short* Wt0 = (unsigned short*)carve(128 * 128 * 2);
    unsigned short* Wt1 = (unsigned short*)carve(128 * 128 * 2);
    unsigned short* Wt2 = (unsigned short*)carve(64 * 128 * 2);

    const int nscan = (N + 255) / 256;
    const int ngemm = (N + 63) / 64;
    const int nagg = (N + 15) / 16;

    // CSR by dst (shared across the 3 layers); single atomic pass
    hipMemsetAsync(counts, 0, (size_t)N * 64, stream);
    rank_kernel<<<(E + 255) / 256, 256, 0, stream>>>(dst, counts, rank, E);
    scan1_kernel<<<nscan, 256, 0, stream>>>(counts, bsum, N);
    scan2_kernel<<<1, 256, 0, stream>>>(bsum, nscan);
    scan3_kernel<<<(N + 1 + 255) / 256, 256, 0, stream>>>(counts, bsum, rowptr, N, E);
    place_kernel<<<(E + 255) / 256, 256, 0, stream>>>(src, dst, edge_weight, rowptr,
                                                      rank, edge_p, E);
    // casts (features -> bf16; all W transposes in one launch)
    fcast_kernel<<<(N * 32 + 255) / 256, 256, 0, stream>>>((const float4*)features,
                                                           (uint2*)f0b, N * 32);
    wcast_all<<<320, 128, 0, stream>>>(W0, W1, W2, Wt0, Wt1, Wt2);

    // Layer 0
    gemm_mfma<8, 4><<<ngemm, 256, 0, stream>>>((const uint4*)f0b, Wt0, al0, ar0,
                                               ftb, el, er, N);
    gat_agg_ln<<<nagg, 256, 0, stream>>>(rowptr, edge_p, (const uint4*)ftb, el, er, lam0,
                                         g0, b0, (const uint4*)f0b, (uint4*)h1, N);
    // Layer 1
    gemm_mfma<8, 4><<<ngemm, 256, 0, stream>>>((const uint4*)h1, Wt1, al1, ar1,
                                               ftb, el, er, N);
    gat_agg_ln<<<nagg, 256, 0, stream>>>(rowptr, edge_p, (const uint4*)ftb, el, er, lam1,
                                         g1, b1, (const uint4*)h1, (uint4*)h2, N);
    // Layer 2
    gemm_mfma<4, 1><<<ngemm, 256, 0, stream>>>((const uint4*)h2, Wt2, al2, ar2,
                                               ftb, el, er, N);
    gat_agg_out<<<nagg, 256, 0, stream>>>(rowptr, edge_p, (const uint2*)ftb,
                                          el, er, lam2, (float*)d_out, N);
}

// Round 10
// 295.297 us; speedup vs baseline: 3.7506x; 1.0426x over previous
//
#include <hip/hip_runtime.h>

#define NEG_SLOPE 0.2f
#define LN_EPS 1e-5f

typedef __attribute__((ext_vector_type(8))) short bf16x8;
typedef __attribute__((ext_vector_type(4))) float f32x4;

__device__ inline unsigned short f2bf(float f) {
    unsigned u = __float_as_uint(f);
    unsigned r = u + 0x7FFFu + ((u >> 16) & 1u);   // round-to-nearest-even
    return (unsigned short)(r >> 16);
}

__device__ inline void unpack8(uint4 u, float* f) {
    f[0] = __uint_as_float(u.x << 16);
    f[1] = __uint_as_float(u.x & 0xFFFF0000u);
    f[2] = __uint_as_float(u.y << 16);
    f[3] = __uint_as_float(u.y & 0xFFFF0000u);
    f[4] = __uint_as_float(u.z << 16);
    f[5] = __uint_as_float(u.z & 0xFFFF0000u);
    f[6] = __uint_as_float(u.w << 16);
    f[7] = __uint_as_float(u.w & 0xFFFF0000u);
}

// ---------------- CSR build + W transpose (fused) ----------------
// counts padded to one per 64B line (atomic serialization, R7). First RB
// blocks: rank[i] = atomicAdd on dst counter. Last 160 blocks: transpose-cast
// the three W matrices (320 rows of 128) to bf16 Wt[n][k].

__global__ void prep_kernel(const int* __restrict__ dst, int* __restrict__ counts,
                            int* __restrict__ rank, int E, int RB,
                            const float* __restrict__ W0, const float* __restrict__ W1,
                            const float* __restrict__ W2, unsigned short* __restrict__ Wt0,
                            unsigned short* __restrict__ Wt1,
                            unsigned short* __restrict__ Wt2) {
    int bid = blockIdx.x;
    if (bid < RB) {
        int i = bid * 256 + threadIdx.x;
        if (i < E) rank[i] = atomicAdd(&counts[dst[i] * 16], 1);
    } else {
        int row = (bid - RB) * 2 + (threadIdx.x >> 7);   // 0..319
        int k = threadIdx.x & 127;
        if (row < 128) {
            Wt0[row * 128 + k] = f2bf(W0[k * 128 + row]);
        } else if (row < 256) {
            int c = row - 128;
            Wt1[c * 128 + k] = f2bf(W1[k * 128 + c]);
        } else {
            int c = row - 256;
            Wt2[c * 128 + k] = f2bf(W2[k * 64 + c]);
        }
    }
}

__global__ __launch_bounds__(256) void scan1_kernel(const int* __restrict__ counts,
                                                    int* __restrict__ bsum, int n) {
    __shared__ int lds[256];
    int t = threadIdx.x;
    int i = blockIdx.x * 256 + t;
    lds[t] = (i < n) ? counts[i * 16] : 0;
    __syncthreads();
    for (int off = 128; off > 0; off >>= 1) {
        int v = (t < off) ? lds[t + off] : 0;
        __syncthreads();
        if (t < off) lds[t] += v;
        __syncthreads();
    }
    if (t == 0) bsum[blockIdx.x] = lds[0];
}

// Fused scan2+scan3: each block scans the (<=256) block sums in LDS to get its
// own exclusive offset, then scans its 256 counts -> rowptr (exclusive).
__global__ __launch_bounds__(256) void scan3_kernel(const int* __restrict__ counts,
                                                    const int* __restrict__ bsum,
                                                    int* __restrict__ rowptr, int n, int E,
                                                    int nscan) {
    __shared__ int lds[256];
    int t = threadIdx.x;
    // pass A: inclusive scan of bsum
    lds[t] = (t < nscan) ? bsum[t] : 0;
    __syncthreads();
    for (int off = 1; off < 256; off <<= 1) {
        int v = (t >= off) ? lds[t - off] : 0;
        __syncthreads();
        lds[t] += v;
        __syncthreads();
    }
    int boff = (blockIdx.x > 0) ? lds[blockIdx.x - 1] : 0;
    __syncthreads();
    // pass B: scan this block's counts
    int i = blockIdx.x * 256 + t;
    int c = (i < n) ? counts[i * 16] : 0;
    lds[t] = c;
    __syncthreads();
    for (int off = 1; off < 256; off <<= 1) {
        int v = (t >= off) ? lds[t - off] : 0;
        __syncthreads();
        lds[t] += v;
        __syncthreads();
    }
    if (i < n) rowptr[i] = boff + lds[t] - c;  // exclusive prefix
    if (i == n) rowptr[n] = E;
}

// Atomic-free placement; record packed to 4B: (bf16(ew)<<16) | src (src<65536).
__global__ void place_kernel(const int* __restrict__ src, const int* __restrict__ dst,
                             const float* __restrict__ ew, const int* __restrict__ rowptr,
                             const int* __restrict__ rank, unsigned* __restrict__ edge_p,
                             int E) {
    int i = blockIdx.x * blockDim.x + threadIdx.x;
    if (i < E) {
        int p = rowptr[dst[i]] + rank[i];
        edge_p[p] = ((unsigned)f2bf(ew[i]) << 16) | (unsigned)src[i];
    }
}

// ---------------- MFMA GEMM + fused el/er + bf16 ft output ----------------
// A32: A is fp32 [n][128] (converted during staging); else bf16 packed rows.

template <int NT, int H, bool A32>
__global__ __launch_bounds__(256) void gemm_mfma(const void* __restrict__ Ap,
                                                 const unsigned short* __restrict__ Wt,
                                                 const float* __restrict__ al,
                                                 const float* __restrict__ ar,
                                                 unsigned short* __restrict__ ftb,
                                                 float* __restrict__ el,
                                                 float* __restrict__ er, int n) {
    constexpr int LDA = 136;  // bf16 elems per LDS row (128 + 8 pad)
    constexpr int D = NT * 16 / H;
    __shared__ unsigned short As[64 * LDA];
    __shared__ unsigned short Ws[NT * 16 * LDA];
    int t = threadIdx.x;
    int row0 = blockIdx.x * 64;

    if constexpr (A32) {
        const float4* A4 = (const float4*)Ap;
        #pragma unroll
        for (int j = 0; j < 8; ++j) {
            int idx = t + j * 256;  // float4 index within 64x128 tile
            int r = idx >> 5;
            int c4 = idx & 31;
            int row = row0 + r;
            float4 v = (row < n) ? A4[(size_t)row * 32 + c4] : make_float4(0.f, 0.f, 0.f, 0.f);
            unsigned p0 = (unsigned)f2bf(v.x) | ((unsigned)f2bf(v.y) << 16);
            unsigned p1 = (unsigned)f2bf(v.z) | ((unsigned)f2bf(v.w) << 16);
            *(uint2*)&As[r * LDA + c4 * 4] = make_uint2(p0, p1);
        }
    } else {
        const uint4* A16 = (const uint4*)Ap;
        #pragma unroll
        for (int j = 0; j < 4; ++j) {
            int idx = t + j * 256;  // uint4 index within 64x128 bf16 tile
            int r = idx >> 4;
            int c8 = idx & 15;
            int row = row0 + r;
            uint4 v = (row < n) ? A16[(size_t)row * 16 + c8] : make_uint4(0, 0, 0, 0);
            *(uint4*)&As[r * LDA + c8 * 8] = v;
        }
    }
    const uint4* Wg = (const uint4*)Wt;
    #pragma unroll
    for (int j = 0; j < NT; ++j) {
        int idx = t + j * 256;
        int r = idx >> 4;
        int c8 = idx & 15;
        *(uint4*)&Ws[r * LDA + c8 * 8] = Wg[idx];
    }
    __syncthreads();

    int w = t >> 6, lane = t & 63;
    int m = lane & 15, q = lane >> 4;
    f32x4 acc[NT] = {};
    const unsigned short* ap = &As[(w * 16 + m) * LDA + q * 8];
    #pragma unroll
    for (int kk = 0; kk < 4; ++kk) {
        bf16x8 a = *(const bf16x8*)(ap + kk * 32);
        #pragma unroll
        for (int nt = 0; nt < NT; ++nt) {
            bf16x8 b = *(const bf16x8*)&Ws[(nt * 16 + m) * LDA + kk * 32 + q * 8];
            acc[nt] = __builtin_amdgcn_mfma_f32_16x16x32_bf16(a, b, acc[nt], 0, 0, 0);
        }
    }

    float alv[NT], arv[NT];
    #pragma unroll
    for (int nt = 0; nt < NT; ++nt) {
        alv[nt] = al[nt * 16 + m];
        arv[nt] = ar[nt * 16 + m];
    }

    int orow = row0 + w * 16 + q * 4;
    #pragma unroll
    for (int r = 0; r < 4; ++r) {
        int row = orow + r;
        float pl[H] = {}, pr[H] = {};
        #pragma unroll
        for (int nt = 0; nt < NT; ++nt) {
            int h = (nt * 16) / D;
            pl[h] = fmaf(acc[nt][r], alv[nt], pl[h]);
            pr[h] = fmaf(acc[nt][r], arv[nt], pr[h]);
        }
        #pragma unroll
        for (int off = 1; off < 16; off <<= 1) {
            #pragma unroll
            for (int h = 0; h < H; ++h) {
                pl[h] += __shfl_xor(pl[h], off, 64);
                pr[h] += __shfl_xor(pr[h], off, 64);
            }
        }
        if (row < n) {
            #pragma unroll
            for (int nt = 0; nt < NT; ++nt)
                ftb[(size_t)row * (NT * 16) + nt * 16 + m] = f2bf(acc[nt][r]);
            if (m < H) {
                float vl = pl[0], vr = pr[0];
                #pragma unroll
                for (int h = 1; h < H; ++h)
                    if (m == h) { vl = pl[h]; vr = pr[h]; }
                el[row * H + m] = vl;
                er[row * H + m] = vr;
            }
        }
    }
}

// ---------------- fused GAT aggregate + ELU + LayerNorm + residual ----------------
// 4 nodes/wave, 16 lanes/node, 8 dims/lane; x4-batched gathers. PREV32: the
// residual input is fp32 (layer 0 reads raw features); else bf16.

__device__ inline void accum8(float* ax, uint4 u, float p) {
    ax[0] = fmaf(p, __uint_as_float(u.x << 16), ax[0]);
    ax[1] = fmaf(p, __uint_as_float(u.x & 0xFFFF0000u), ax[1]);
    ax[2] = fmaf(p, __uint_as_float(u.y << 16), ax[2]);
    ax[3] = fmaf(p, __uint_as_float(u.y & 0xFFFF0000u), ax[3]);
    ax[4] = fmaf(p, __uint_as_float(u.z << 16), ax[4]);
    ax[5] = fmaf(p, __uint_as_float(u.z & 0xFFFF0000u), ax[5]);
    ax[6] = fmaf(p, __uint_as_float(u.w << 16), ax[6]);
    ax[7] = fmaf(p, __uint_as_float(u.w & 0xFFFF0000u), ax[7]);
}

template <bool PREV32>
__global__ __launch_bounds__(256) void gat_agg_ln(
    const int* __restrict__ rowptr, const unsigned* __restrict__ edge_p,
    const uint4* __restrict__ ftb4, const float* __restrict__ el,
    const float* __restrict__ er, const float* __restrict__ lam_p,
    const float* __restrict__ g, const float* __restrict__ b,
    const void* __restrict__ prevp, uint4* __restrict__ outb, int n) {
    int node = blockIdx.x * 16 + (threadIdx.x >> 4);
    if (node >= n) return;
    int li = threadIdx.x & 15;
    int head = li >> 2;
    float lam = lam_p[0];
    float erv = er[node * 4 + head];
    int s0 = rowptr[node], s1 = rowptr[node + 1];
    float ax[8] = {};
    float s = 0.f;

    int i = s0;
    for (; i + 4 <= s1; i += 4) {
        unsigned e0 = edge_p[i], e1 = edge_p[i + 1], e2 = edge_p[i + 2], e3 = edge_p[i + 3];
        unsigned sn0 = e0 & 0xFFFFu, sn1 = e1 & 0xFFFFu, sn2 = e2 & 0xFFFFu, sn3 = e3 & 0xFFFFu;
        uint4 u0 = ftb4[(size_t)sn0 * 16 + li];
        uint4 u1 = ftb4[(size_t)sn1 * 16 + li];
        uint4 u2 = ftb4[(size_t)sn2 * 16 + li];
        uint4 u3 = ftb4[(size_t)sn3 * 16 + li];
        float l0 = el[sn0 * 4 + head];
        float l1 = el[sn1 * 4 + head];
        float l2 = el[sn2 * 4 + head];
        float l3 = el[sn3 * 4 + head];
        float v0 = l0 + erv + lam * __uint_as_float(e0 & 0xFFFF0000u);
        float v1 = l1 + erv + lam * __uint_as_float(e1 & 0xFFFF0000u);
        float v2 = l2 + erv + lam * __uint_as_float(e2 & 0xFFFF0000u);
        float v3 = l3 + erv + lam * __uint_as_float(e3 & 0xFFFF0000u);
        v0 = fmaxf(v0, NEG_SLOPE * v0);
        v1 = fmaxf(v1, NEG_SLOPE * v1);
        v2 = fmaxf(v2, NEG_SLOPE * v2);
        v3 = fmaxf(v3, NEG_SLOPE * v3);
        float p0 = __expf(v0), p1 = __expf(v1), p2 = __expf(v2), p3 = __expf(v3);
        accum8(ax, u0, p0);
        accum8(ax, u1, p1);
        accum8(ax, u2, p2);
        accum8(ax, u3, p3);
        s += (p0 + p1) + (p2 + p3);
    }
    for (; i < s1; ++i) {
        unsigned e = edge_p[i];
        unsigned sn = e & 0xFFFFu;
        uint4 u = ftb4[(size_t)sn * 16 + li];
        float v = el[sn * 4 + head] + erv + lam * __uint_as_float(e & 0xFFFF0000u);
        v = fmaxf(v, NEG_SLOPE * v);
        float p = __expf(v);
        accum8(ax, u, p);
        s += p;
    }

    float inv = (s > 0.f) ? 1.f / s : 0.f;
    float x[8];
    float sum = 0.f, sq = 0.f;
    #pragma unroll
    for (int d = 0; d < 8; ++d) {
        float v = ax[d] * inv;
        v = (v > 0.f) ? v : expm1f(v);
        x[d] = v;
        sum += v;
        sq += v * v;
    }
    #pragma unroll
    for (int off = 1; off < 16; off <<= 1) {
        sum += __shfl_xor(sum, off, 16);
        sq += __shfl_xor(sq, off, 16);
    }
    float mu = sum * (1.f / 128.f);
    float var = sq * (1.f / 128.f) - mu * mu;
    float rs = rsqrtf(var + LN_EPS);

    const float4* g4 = (const float4*)g;
    const float4* b4 = (const float4*)b;
    float pv[8];
    if constexpr (PREV32) {
        const float4* p4 = (const float4*)prevp;
        #pragma unroll
        for (int h = 0; h < 2; ++h) {
            float4 v = p4[(size_t)node * 32 + li * 2 + h];
            pv[h * 4 + 0] = v.x; pv[h * 4 + 1] = v.y;
            pv[h * 4 + 2] = v.z; pv[h * 4 + 3] = v.w;
        }
    } else {
        unpack8(((const uint4*)prevp)[(size_t)node * 16 + li], pv);
    }
    float y[8];
    #pragma unroll
    for (int h = 0; h < 2; ++h) {
        float4 gv = g4[li * 2 + h];
        float4 bv = b4[li * 2 + h];
        y[h * 4 + 0] = (x[h * 4 + 0] - mu) * rs * gv.x + bv.x + pv[h * 4 + 0];
        y[h * 4 + 1] = (x[h * 4 + 1] - mu) * rs * gv.y + bv.y + pv[h * 4 + 1];
        y[h * 4 + 2] = (x[h * 4 + 2] - mu) * rs * gv.z + bv.z + pv[h * 4 + 2];
        y[h * 4 + 3] = (x[h * 4 + 3] - mu) * rs * gv.w + bv.w + pv[h * 4 + 3];
    }
    uint4 o;
    o.x = (unsigned)f2bf(y[0]) | ((unsigned)f2bf(y[1]) << 16);
    o.y = (unsigned)f2bf(y[2]) | ((unsigned)f2bf(y[3]) << 16);
    o.z = (unsigned)f2bf(y[4]) | ((unsigned)f2bf(y[5]) << 16);
    o.w = (unsigned)f2bf(y[6]) | ((unsigned)f2bf(y[7]) << 16);
    outb[(size_t)node * 16 + li] = o;
}

// Layer 2: H=1, OUT=64; 4 nodes/wave, 16 lanes/node, 4 dims/lane (uint2), x4 batch.
__global__ __launch_bounds__(256) void gat_agg_out(
    const int* __restrict__ rowptr, const unsigned* __restrict__ edge_p,
    const uint2* __restrict__ ftb2, const float* __restrict__ el,
    const float* __restrict__ er, const float* __restrict__ lam_p,
    float* __restrict__ out, int n) {
    int node = blockIdx.x * 16 + (threadIdx.x >> 4);
    if (node >= n) return;
    int li = threadIdx.x & 15;
    float lam = lam_p[0];
    float erv = er[node];
    int s0 = rowptr[node], s1 = rowptr[node + 1];
    float ax[4] = {};
    float s = 0.f;

    int i = s0;
    for (; i + 4 <= s1; i += 4) {
        unsigned e0 = edge_p[i], e1 = edge_p[i + 1], e2 = edge_p[i + 2], e3 = edge_p[i + 3];
        unsigned sn0 = e0 & 0xFFFFu, sn1 = e1 & 0xFFFFu, sn2 = e2 & 0xFFFFu, sn3 = e3 & 0xFFFFu;
        uint2 u0 = ftb2[(size_t)sn0 * 16 + li];
        uint2 u1 = ftb2[(size_t)sn1 * 16 + li];
        uint2 u2 = ftb2[(size_t)sn2 * 16 + li];
        uint2 u3 = ftb2[(size_t)sn3 * 16 + li];
        float l0 = el[sn0], l1 = el[sn1], l2 = el[sn2], l3 = el[sn3];
        float v0 = l0 + erv + lam * __uint_as_float(e0 & 0xFFFF0000u);
        float v1 = l1 + erv + lam * __uint_as_float(e1 & 0xFFFF0000u);
        float v2 = l2 + erv + lam * __uint_as_float(e2 & 0xFFFF0000u);
        float v3 = l3 + erv + lam * __uint_as_float(e3 & 0xFFFF0000u);
        v0 = fmaxf(v0, NEG_SLOPE * v0);
        v1 = fmaxf(v1, NEG_SLOPE * v1);
        v2 = fmaxf(v2, NEG_SLOPE * v2);
        v3 = fmaxf(v3, NEG_SLOPE * v3);
        float p0 = __expf(v0), p1 = __expf(v1), p2 = __expf(v2), p3 = __expf(v3);
        ax[0] = fmaf(p0, __uint_as_float(u0.x << 16), ax[0]);
        ax[1] = fmaf(p0, __uint_as_float(u0.x & 0xFFFF0000u), ax[1]);
        ax[2] = fmaf(p0, __uint_as_float(u0.y << 16), ax[2]);
        ax[3] = fmaf(p0, __uint_as_float(u0.y & 0xFFFF0000u), ax[3]);
        ax[0] = fmaf(p1, __uint_as_float(u1.x << 16), ax[0]);
        ax[1] = fmaf(p1, __uint_as_float(u1.x & 0xFFFF0000u), ax[1]);
        ax[2] = fmaf(p1, __uint_as_float(u1.y << 16), ax[2]);
        ax[3] = fmaf(p1, __uint_as_float(u1.y & 0xFFFF0000u), ax[3]);
        ax[0] = fmaf(p2, __uint_as_float(u2.x << 16), ax[0]);
        ax[1] = fmaf(p2, __uint_as_float(u2.x & 0xFFFF0000u), ax[1]);
        ax[2] = fmaf(p2, __uint_as_float(u2.y << 16), ax[2]);
        ax[3] = fmaf(p2, __uint_as_float(u2.y & 0xFFFF0000u), ax[3]);
        ax[0] = fmaf(p3, __uint_as_float(u3.x << 16), ax[0]);
        ax[1] = fmaf(p3, __uint_as_float(u3.x & 0xFFFF0000u), ax[1]);
        ax[2] = fmaf(p3, __uint_as_float(u3.y << 16), ax[2]);
        ax[3] = fmaf(p3, __uint_as_float(u3.y & 0xFFFF0000u), ax[3]);
        s += (p0 + p1) + (p2 + p3);
    }
    for (; i < s1; ++i) {
        unsigned e = edge_p[i];
        unsigned sn = e & 0xFFFFu;
        uint2 u = ftb2[(size_t)sn * 16 + li];
        float v = el[sn] + erv + lam * __uint_as_float(e & 0xFFFF0000u);
        v = fmaxf(v, NEG_SLOPE * v);
        float p = __expf(v);
        ax[0] = fmaf(p, __uint_as_float(u.x << 16), ax[0]);
        ax[1] = fmaf(p, __uint_as_float(u.x & 0xFFFF0000u), ax[1]);
        ax[2] = fmaf(p, __uint_as_float(u.y << 16), ax[2]);
        ax[3] = fmaf(p, __uint_as_float(u.y & 0xFFFF0000u), ax[3]);
        s += p;
    }

    float inv = (s > 0.f) ? 1.f / s : 0.f;
    float4 y;
    y.x = ax[0] * inv;
    y.y = ax[1] * inv;
    y.z = ax[2] * inv;
    y.w = ax[3] * inv;
    ((float4*)out)[(size_t)node * 16 + li] = y;
    ((float4*)out)[(size_t)(n + node) * 16 + li] = y;
}

// ---------------- launch ----------------

extern "C" void kernel_launch(void* const* d_in, const int* in_sizes, int n_in,
                              void* d_out, int out_size, void* d_ws, size_t ws_size,
                              hipStream_t stream) {
    const float* features = (const float*)d_in[0];
    const float* edge_weight = (const float*)d_in[1];
    const int* src = (const int*)d_in[2];
    const int* dst = (const int*)d_in[3];
    const float* W0 = (const float*)d_in[4];
    const float* al0 = (const float*)d_in[5];
    const float* ar0 = (const float*)d_in[6];
    const float* lam0 = (const float*)d_in[7];
    const float* W1 = (const float*)d_in[8];
    const float* al1 = (const float*)d_in[9];
    const float* ar1 = (const float*)d_in[10];
    const float* lam1 = (const float*)d_in[11];
    const float* W2 = (const float*)d_in[12];
    const float* al2 = (const float*)d_in[13];
    const float* ar2 = (const float*)d_in[14];
    const float* lam2 = (const float*)d_in[15];
    const float* g0 = (const float*)d_in[16];
    const float* b0 = (const float*)d_in[17];
    const float* g1 = (const float*)d_in[18];
    const float* b1 = (const float*)d_in[19];

    const int N = in_sizes[0] / 128;   // 50000 (< 65536: src fits 16 bits)
    const int E = in_sizes[1];

    char* w = (char*)d_ws;
    size_t o = 0;
    auto carve = [&](size_t bytes) {
        char* p = w + o;
        o += (bytes + 255) & ~(size_t)255;
        return p;
    };
    int* counts = (int*)carve((size_t)N * 64);       // 1 counter per 64B line
    int* rowptr = (int*)carve((size_t)(N + 1) * 4);
    int* bsum = (int*)carve(256 * 4);
    int* rank = (int*)carve((size_t)E * 4);
    unsigned* edge_p = (unsigned*)carve((size_t)E * 4);
    unsigned short* ftb = (unsigned short*)carve((size_t)N * 128 * 2);
    unsigned short* h1 = (unsigned short*)carve((size_t)N * 128 * 2);
    unsigned short* h2 = (unsigned short*)carve((size_t)N * 128 * 2);
    float* el = (float*)carve((size_t)N * 4 * 4);
    float* er = (float*)carve((size_t)N * 4 * 4);
    unsigned short* Wt0 = (unsigned short*)carve(128 * 128 * 2);
    unsigned short* Wt1 = (unsigned short*)carve(128 * 128 * 2);
    unsigned short* Wt2 = (unsigned short*)carve(64 * 128 * 2);

    const int nscan = (N + 255) / 256;            // 196 (<=256 required by scan3)
    const int ngemm = (N + 63) / 64;
    const int nagg = (N + 15) / 16;
    const int RB = (E + 255) / 256;

    // CSR by dst (shared across the 3 layers) + W transposes, fused
    hipMemsetAsync(counts, 0, (size_t)N * 64, stream);
    prep_kernel<<<RB + 160, 256, 0, stream>>>(dst, counts, rank, E, RB,
                                              W0, W1, W2, Wt0, Wt1, Wt2);
    scan1_kernel<<<nscan, 256, 0, stream>>>(counts, bsum, N);
    scan3_kernel<<<(N + 1 + 255) / 256, 256, 0, stream>>>(counts, bsum, rowptr, N, E, nscan);
    place_kernel<<<(E + 255) / 256, 256, 0, stream>>>(src, dst, edge_weight, rowptr,
                                                      rank, edge_p, E);

    // Layer 0 (fp32 A, fp32 residual)
    gemm_mfma<8, 4, true><<<ngemm, 256, 0, stream>>>(features, Wt0, al0, ar0,
                                                     ftb, el, er, N);
    gat_agg_ln<true><<<nagg, 256, 0, stream>>>(rowptr, edge_p, (const uint4*)ftb, el, er,
                                               lam0, g0, b0, features, (uint4*)h1, N);
    // Layer 1
    gemm_mfma<8, 4, false><<<ngemm, 256, 0, stream>>>(h1, Wt1, al1, ar1, ftb, el, er, N);
    gat_agg_ln<false><<<nagg, 256, 0, stream>>>(rowptr, edge_p, (const uint4*)ftb, el, er,
                                                lam1, g1, b1, h1, (uint4*)h2, N);
    // Layer 2
    gemm_mfma<4, 1, false><<<ngemm, 256, 0, stream>>>(h2, Wt2, al2, ar2, ftb, el, er, N);
    gat_agg_out<<<nagg, 256, 0, stream>>>(rowptr, edge_p, (const uint2*)ftb,
                                          el, er, lam2, (float*)d_out, N);
}